// Round 6
// baseline (527.123 us; speedup 1.0000x reference)
//
#include <hip/hip_runtime.h>
#include <hip/hip_bf16.h>
#include <stdint.h>

#define BN_EPS 1e-5f

typedef __attribute__((ext_vector_type(8)))  short bf16x8;
typedef __attribute__((ext_vector_type(16))) float f32x16;

static __device__ __forceinline__ float bflo2f(uint32_t p){
  union { uint32_t u; float f; } c; c.u = p << 16; return c.f;
}
static __device__ __forceinline__ float bfhi2f(uint32_t p){
  union { uint32_t u; float f; } c; c.u = p & 0xffff0000u; return c.f;
}
static __device__ __forceinline__ uint16_t f2bf(float f){
  union { float f; uint32_t u; } c; c.f = f;
  uint32_t u = c.u;
  return (uint16_t)((u + 0x7fffu + ((u >> 16) & 1u)) >> 16);
}
static __device__ __forceinline__ uint32_t pack2(float a, float b){
  return (uint32_t)f2bf(a) | ((uint32_t)f2bf(b) << 16);
}

// ---------------- prepass: h fp32->bf16, W transpose+swizzle, zero stats/bar ----------------
__global__ void k_prep(const float* __restrict__ h, uint16_t* __restrict__ hb, int hblocks,
                       const float* __restrict__ W1, const float* __restrict__ W2,
                       uint16_t* __restrict__ Wt1, uint16_t* __restrict__ Wt2,
                       float* __restrict__ stats, int* __restrict__ bar){
  if (blockIdx.x == gridDim.x - 1){
    if (threadIdx.x < 128){
      float4 z = make_float4(0.f, 0.f, 0.f, 0.f);
      *(float4*)(stats + threadIdx.x * 4) = z;
    } else if (threadIdx.x == 128){
      *bar = 0;
    }
  }
  if ((int)blockIdx.x < hblocks){
    int i = (blockIdx.x * 256 + threadIdx.x) * 8;
    float4 a = *(const float4*)(h + i);
    float4 b = *(const float4*)(h + i + 4);
    uint4 o;
    o.x = pack2(a.x, a.y); o.y = pack2(a.z, a.w);
    o.z = pack2(b.x, b.y); o.w = pack2(b.z, b.w);
    *(uint4*)(hb + i) = o;
    return;
  }
  int gid = (blockIdx.x - hblocks) * 256 + threadIdx.x;
  if (gid >= 4096) return;
  const float* Wf = (gid < 2048) ? W1 : W2;
  uint16_t* Wt = (gid < 2048) ? Wt1 : Wt2;
  int cid = gid & 2047;
  int nrow = cid >> 4;
  int c    = cid & 15;
  int k0 = c * 8;
  float e[8];
  #pragma unroll
  for (int j = 0; j < 8; ++j) e[j] = Wf[(k0 + j) * 128 + nrow];
  uint4 o;
  o.x = pack2(e[0], e[1]); o.y = pack2(e[2], e[3]);
  o.z = pack2(e[4], e[5]); o.w = pack2(e[6], e[7]);
  int cs = c ^ (nrow & 15);
  *(uint4*)(Wt + nrow * 128 + cs * 8) = o;
}

// ---------------- device-scope grid barrier (all blocks co-resident) ----------------
static __device__ __forceinline__ void gridbar(int* bar, int nblocks, int phase){
  __syncthreads();
  if (threadIdx.x == 0){
    __hip_atomic_fetch_add(bar, 1, __ATOMIC_RELEASE, __HIP_MEMORY_SCOPE_AGENT);
    int target = nblocks * phase;
    while (__hip_atomic_load(bar, __ATOMIC_ACQUIRE, __HIP_MEMORY_SCOPE_AGENT) < target){
      __builtin_amdgcn_s_sleep(8);
    }
  }
  __syncthreads();
}

// ---------------- fused CSR build: hist -> colscan -> bscan -> bin -> csr ----------------
__global__ __launch_bounds__(256, 4) void k_csr_all(
    const int* __restrict__ src, const int* __restrict__ dst,
    int* __restrict__ M, int* __restrict__ btot, int* __restrict__ bbase,
    int* __restrict__ row_off, int* __restrict__ col_idx, uint2* __restrict__ binned,
    int* __restrict__ bar, int E, int n, int NB, int EB, int NG){
  __shared__ int sm[1024];
  int b = blockIdx.x, t = threadIdx.x;

  // ---- phase A: per-chunk histogram ----
  if (b < EB){
    sm[t] = 0; sm[t + 256] = 0;
    __syncthreads();
    int base = b * 4096;
    #pragma unroll 4
    for (int j = t; j < 4096; j += 256){
      int i = base + j;
      if (i < E) atomicAdd(&sm[dst[i] >> 8], 1);
    }
    __syncthreads();
    size_t row = (size_t)b * NB;
    if (t < NB) M[row + t] = sm[t];
    int t2 = t + 256;
    if (t2 < NB) M[row + t2] = sm[t2];
  }
  gridbar(bar, NG, 1);

  // ---- phase B: column scan (bucket b over EB chunks) ----
  if (b < NB){
    int i0 = 2 * t, i1 = 2 * t + 1;
    int v0 = (i0 < EB) ? M[(size_t)i0 * NB + b] : 0;
    int v1 = (i1 < EB) ? M[(size_t)i1 * NB + b] : 0;
    sm[t] = v0 + v1;
    __syncthreads();
    for (int off = 1; off < 256; off <<= 1){
      int v = (t >= off) ? sm[t - off] : 0;
      __syncthreads();
      sm[t] += v;
      __syncthreads();
    }
    int excl = sm[t] - (v0 + v1);
    if (i0 < EB) M[(size_t)i0 * NB + b] = excl;
    if (i1 < EB) M[(size_t)i1 * NB + b] = excl + v0;
    if (t == 255) btot[b] = sm[255];
  }
  gridbar(bar, NG, 2);

  // ---- phase C: bucket base scan (block 0) ----
  if (b == 0){
    int i0 = 2 * t, i1 = 2 * t + 1;
    int v0 = (i0 < NB) ? btot[i0] : 0;
    int v1 = (i1 < NB) ? btot[i1] : 0;
    sm[t] = v0 + v1;
    __syncthreads();
    for (int off = 1; off < 256; off <<= 1){
      int v = (t >= off) ? sm[t - off] : 0;
      __syncthreads();
      sm[t] += v;
      __syncthreads();
    }
    int excl = sm[t] - (v0 + v1);
    if (i0 < NB) bbase[i0] = excl;
    if (i1 < NB) bbase[i1] = excl + v0;
    if (t == 0){ bbase[NB] = E; row_off[n] = E; }
  }
  gridbar(bar, NG, 3);

  // ---- phase D: bin edges ----
  if (b < EB){
    size_t row = (size_t)b * NB;
    if (t < NB) sm[t] = bbase[t] + M[row + t];
    int t2 = t + 256;
    if (t2 < NB) sm[t2] = bbase[t2] + M[row + t2];
    sm[512 + t] = 0; sm[768 + t] = 0;
    __syncthreads();
    int base = b * 4096;
    #pragma unroll 4
    for (int j = t; j < 4096; j += 256){
      int i = base + j;
      if (i < E){
        int d = dst[i];
        int bk = d >> 8;
        int r = atomicAdd(&sm[512 + bk], 1);
        binned[sm[bk] + r] = make_uint2((unsigned)src[i], (unsigned)d);
      }
    }
  }
  gridbar(bar, NG, 4);

  // ---- phase E: per-bucket CSR ----
  if (b < NB){
    int e0 = bbase[b], e1 = bbase[b + 1];
    int nb0 = b << 8;
    sm[t] = 0;        // cnt
    sm[512 + t] = 0;  // cur
    __syncthreads();
    int m = e1 - e0;
    for (int j = t; j < m; j += 256) atomicAdd(&sm[binned[e0 + j].y & 255], 1);
    __syncthreads();
    int v = sm[t];
    sm[256 + t] = v;  // off
    __syncthreads();
    for (int o = 1; o < 256; o <<= 1){
      int u = (t >= o) ? sm[256 + t - o] : 0;
      __syncthreads();
      sm[256 + t] += u;
      __syncthreads();
    }
    int excl = sm[256 + t] - v;
    __syncthreads();
    sm[256 + t] = excl;
    if (nb0 + t < n) row_off[nb0 + t] = e0 + excl;
    __syncthreads();
    for (int j = t; j < m; j += 256){
      uint2 p = binned[e0 + j];
      int dl = p.y & 255;
      int r = atomicAdd(&sm[512 + dl], 1);
      col_idx[e0 + sm[256 + dl] + r] = (int)p.x;
    }
  }
}

// -------- gather: 16 lanes per row (16B/lane), up to 16 neighbors in flight --------
__global__ void k_gather(const uint16_t* __restrict__ hb, const int* __restrict__ row_off,
                         const int* __restrict__ col_idx, const float* __restrict__ eps_p,
                         uint16_t* __restrict__ Xb, int n){
  int node = (blockIdx.x << 2) + (threadIdx.x >> 6);
  int lane = threadIdx.x & 63;
  if (node >= n) return;
  int g = lane >> 4;
  int c = lane & 15;
  const uint4* hp4 = (const uint4*)hb;
  int j = row_off[node], jend = row_off[node + 1];
  float a0=0.f,a1=0.f,a2=0.f,a3=0.f,a4=0.f,a5=0.f,a6=0.f,a7=0.f;
  for (; j + 16 <= jend; j += 16){
    int sA = col_idx[j + g];
    int sB = col_idx[j + 4 + g];
    int sC = col_idx[j + 8 + g];
    int sD = col_idx[j + 12 + g];
    uint4 vA = hp4[(size_t)sA * 16 + c];
    uint4 vB = hp4[(size_t)sB * 16 + c];
    uint4 vC = hp4[(size_t)sC * 16 + c];
    uint4 vD = hp4[(size_t)sD * 16 + c];
    a0 += (bflo2f(vA.x) + bflo2f(vB.x)) + (bflo2f(vC.x) + bflo2f(vD.x));
    a1 += (bfhi2f(vA.x) + bfhi2f(vB.x)) + (bfhi2f(vC.x) + bfhi2f(vD.x));
    a2 += (bflo2f(vA.y) + bflo2f(vB.y)) + (bflo2f(vC.y) + bflo2f(vD.y));
    a3 += (bfhi2f(vA.y) + bfhi2f(vB.y)) + (bfhi2f(vC.y) + bfhi2f(vD.y));
    a4 += (bflo2f(vA.z) + bflo2f(vB.z)) + (bflo2f(vC.z) + bflo2f(vD.z));
    a5 += (bfhi2f(vA.z) + bfhi2f(vB.z)) + (bfhi2f(vC.z) + bfhi2f(vD.z));
    a6 += (bflo2f(vA.w) + bflo2f(vB.w)) + (bflo2f(vC.w) + bflo2f(vD.w));
    a7 += (bfhi2f(vA.w) + bfhi2f(vB.w)) + (bfhi2f(vC.w) + bfhi2f(vD.w));
  }
  for (; j + 8 <= jend; j += 8){
    int sA = col_idx[j + g];
    int sB = col_idx[j + 4 + g];
    uint4 vA = hp4[(size_t)sA * 16 + c];
    uint4 vB = hp4[(size_t)sB * 16 + c];
    a0 += bflo2f(vA.x) + bflo2f(vB.x);
    a1 += bfhi2f(vA.x) + bfhi2f(vB.x);
    a2 += bflo2f(vA.y) + bflo2f(vB.y);
    a3 += bfhi2f(vA.y) + bfhi2f(vB.y);
    a4 += bflo2f(vA.z) + bflo2f(vB.z);
    a5 += bfhi2f(vA.z) + bfhi2f(vB.z);
    a6 += bflo2f(vA.w) + bflo2f(vB.w);
    a7 += bfhi2f(vA.w) + bfhi2f(vB.w);
  }
  for (; j + 4 <= jend; j += 4){
    int s = col_idx[j + g];
    uint4 v = hp4[(size_t)s * 16 + c];
    a0 += bflo2f(v.x); a1 += bfhi2f(v.x);
    a2 += bflo2f(v.y); a3 += bfhi2f(v.y);
    a4 += bflo2f(v.z); a5 += bfhi2f(v.z);
    a6 += bflo2f(v.w); a7 += bfhi2f(v.w);
  }
  int rem = jend - j;
  if (rem > 0){
    int jj = j + (g < rem ? g : rem - 1);
    float w = (g < rem) ? 1.f : 0.f;
    int s = col_idx[jj];
    uint4 v = hp4[(size_t)s * 16 + c];
    a0 = fmaf(w, bflo2f(v.x), a0); a1 = fmaf(w, bfhi2f(v.x), a1);
    a2 = fmaf(w, bflo2f(v.y), a2); a3 = fmaf(w, bfhi2f(v.y), a3);
    a4 = fmaf(w, bflo2f(v.z), a4); a5 = fmaf(w, bfhi2f(v.z), a5);
    a6 = fmaf(w, bflo2f(v.w), a6); a7 = fmaf(w, bfhi2f(v.w), a7);
  }
  a0 += __shfl_xor(a0, 16); a1 += __shfl_xor(a1, 16);
  a2 += __shfl_xor(a2, 16); a3 += __shfl_xor(a3, 16);
  a4 += __shfl_xor(a4, 16); a5 += __shfl_xor(a5, 16);
  a6 += __shfl_xor(a6, 16); a7 += __shfl_xor(a7, 16);
  a0 += __shfl_xor(a0, 32); a1 += __shfl_xor(a1, 32);
  a2 += __shfl_xor(a2, 32); a3 += __shfl_xor(a3, 32);
  a4 += __shfl_xor(a4, 32); a5 += __shfl_xor(a5, 32);
  a6 += __shfl_xor(a6, 32); a7 += __shfl_xor(a7, 32);
  if (g == 0){
    float ce = 1.0f + eps_p[0];
    uint4 vh = hp4[(size_t)node * 16 + c];
    a0 = fmaf(ce, bflo2f(vh.x), a0); a1 = fmaf(ce, bfhi2f(vh.x), a1);
    a2 = fmaf(ce, bflo2f(vh.y), a2); a3 = fmaf(ce, bfhi2f(vh.y), a3);
    a4 = fmaf(ce, bflo2f(vh.z), a4); a5 = fmaf(ce, bfhi2f(vh.z), a5);
    a6 = fmaf(ce, bflo2f(vh.w), a6); a7 = fmaf(ce, bfhi2f(vh.w), a7);
    uint4 o;
    o.x = pack2(a0, a1); o.y = pack2(a2, a3);
    o.z = pack2(a4, a5); o.w = pack2(a6, a7);
    *((uint4*)Xb + (size_t)node * 16 + c) = o;
  }
}

// -------- MFMA GEMM; BN_IN computes BN coefs in-kernel from previous layer's sums --------
template<bool BN_IN>
__global__ __launch_bounds__(256, 3) void k_mgemm(
    const uint16_t* __restrict__ Ag, const uint16_t* __restrict__ Wt,
    const float* __restrict__ bias_f,
    const float* __restrict__ sin, const float* __restrict__ sqin,
    const float* __restrict__ gin, const float* __restrict__ bein, float invN,
    uint16_t* __restrict__ Yout, float* __restrict__ osum, float* __restrict__ osq, int n){
  __shared__ __align__(16) uint16_t Al[64 * 128];
  __shared__ __align__(16) uint16_t Wl[128 * 128];
  __shared__ float csum[128], csq[128];
  __shared__ __align__(16) float ABl[256];
  int tid = threadIdx.x;
  int rbase = blockIdx.x * 64;

  if (BN_IN){
    if (tid < 128){
      float mu = sin[tid] * invN;
      float var = sqin[tid] * invN - mu * mu;
      float A = gin[tid] * rsqrtf(var + BN_EPS);
      ABl[tid] = A;
      ABl[128 + tid] = bein[tid] - mu * A;
    }
    __syncthreads();
  }

  {
    const uint4* g = (const uint4*)Wt;
    uint4* d = (uint4*)Wl;
    #pragma unroll
    for (int i = 0; i < 8; ++i) d[tid + 256 * i] = g[tid + 256 * i];
  }
  #pragma unroll
  for (int i = 0; i < 4; ++i){
    int f = tid + 256 * i;
    int m = f >> 4, c = f & 15;
    int gr = rbase + m;
    uint4 v = make_uint4(0, 0, 0, 0);
    if (gr < n){
      v = *(const uint4*)(Ag + (size_t)gr * 128 + c * 8);
      if (BN_IN){
        int k0 = c * 8;
        float4 ka0 = *(const float4*)(ABl + k0);
        float4 ka1 = *(const float4*)(ABl + k0 + 4);
        float4 kb0 = *(const float4*)(ABl + 128 + k0);
        float4 kb1 = *(const float4*)(ABl + 128 + k0 + 4);
        float e0 = fmaxf(fmaf(bflo2f(v.x), ka0.x, kb0.x), 0.f);
        float e1 = fmaxf(fmaf(bfhi2f(v.x), ka0.y, kb0.y), 0.f);
        float e2 = fmaxf(fmaf(bflo2f(v.y), ka0.z, kb0.z), 0.f);
        float e3 = fmaxf(fmaf(bfhi2f(v.y), ka0.w, kb0.w), 0.f);
        float e4 = fmaxf(fmaf(bflo2f(v.z), ka1.x, kb1.x), 0.f);
        float e5 = fmaxf(fmaf(bfhi2f(v.z), ka1.y, kb1.y), 0.f);
        float e6 = fmaxf(fmaf(bflo2f(v.w), ka1.z, kb1.z), 0.f);
        float e7 = fmaxf(fmaf(bfhi2f(v.w), ka1.w, kb1.w), 0.f);
        v.x = pack2(e0, e1); v.y = pack2(e2, e3);
        v.z = pack2(e4, e5); v.w = pack2(e6, e7);
      }
    }
    *(uint4*)((char*)Al + m * 256 + ((c ^ (m & 15)) * 16)) = v;
  }
  if (tid < 128){ csum[tid] = 0.f; csq[tid] = 0.f; }
  __syncthreads();

  int lane = tid & 63;
  int w    = tid >> 6;
  int hi   = lane >> 5;
  int key  = lane & 15;
  int m0   = (w & 1) * 32;
  int n0   = (w >> 1) * 64;
  int mrow = m0 + (lane & 31);
  int nrow0 = n0 + (lane & 31);
  int nrow1 = nrow0 + 32;

  f32x16 acc0, acc1;
  #pragma unroll
  for (int i = 0; i < 16; ++i){ acc0[i] = 0.f; acc1[i] = 0.f; }

  const char* Ab = (const char*)Al;
  const char* Wb = (const char*)Wl;
  #pragma unroll
  for (int kt = 0; kt < 8; ++kt){
    int cs = ((2 * kt + hi) ^ key) * 16;
    bf16x8 a  = *(const bf16x8*)(Ab + mrow  * 256 + cs);
    bf16x8 b0 = *(const bf16x8*)(Wb + nrow0 * 256 + cs);
    bf16x8 b1 = *(const bf16x8*)(Wb + nrow1 * 256 + cs);
    acc0 = __builtin_amdgcn_mfma_f32_32x32x16_bf16(a, b0, acc0, 0, 0, 0);
    acc1 = __builtin_amdgcn_mfma_f32_32x32x16_bf16(a, b1, acc1, 0, 0, 0);
  }
  __syncthreads();

  uint16_t* Yl = Wl;
  float bias0 = bias_f[nrow0];
  float bias1 = bias_f[nrow1];
  float ps0 = 0.f, pq0 = 0.f, ps1 = 0.f, pq1 = 0.f;
  #pragma unroll
  for (int r = 0; r < 16; ++r){
    int row = m0 + (r & 3) + 8 * (r >> 2) + 4 * hi;
    bool valid = (rbase + row) < n;
    float y0 = acc0[r] + bias0;
    float y1 = acc1[r] + bias1;
    if (valid){
      ps0 += y0; pq0 += y0 * y0;
      ps1 += y1; pq1 += y1 * y1;
    }
    Yl[row * 128 + nrow0] = f2bf(y0);
    Yl[row * 128 + nrow1] = f2bf(y1);
  }
  atomicAdd(&csum[nrow0], ps0); atomicAdd(&csq[nrow0], pq0);
  atomicAdd(&csum[nrow1], ps1); atomicAdd(&csq[nrow1], pq1);
  __syncthreads();

  #pragma unroll
  for (int i = 0; i < 4; ++i){
    int id = tid + 256 * i;
    int row = id >> 4, c = id & 15;
    int gr = rbase + row;
    if (gr < n)
      *((uint4*)Yout + (size_t)gr * 16 + c) = *((const uint4*)Yl + id);
  }
  if (tid < 128){
    atomicAdd(&osum[tid], csum[tid]);
    atomicAdd(&osq[tid], csq[tid]);
  }
}

// -------- final: BN2 coefs computed per-block, then BN+ReLU, fp32 out --------
__global__ void k_final(const uint16_t* __restrict__ Y2b,
                        const float* __restrict__ sum2, const float* __restrict__ sq2,
                        const float* __restrict__ g2, const float* __restrict__ be2, float invN,
                        float* __restrict__ out, int total){
  __shared__ __align__(16) float AB[256];
  int tid = threadIdx.x;
  if (tid < 128){
    float mu = sum2[tid] * invN;
    float var = sq2[tid] * invN - mu * mu;
    float A = g2[tid] * rsqrtf(var + BN_EPS);
    AB[tid] = A;
    AB[128 + tid] = be2[tid] - mu * A;
  }
  __syncthreads();
  int i = (blockIdx.x * 256 + tid) * 4;
  if (i >= total) return;
  uint2 v = *(const uint2*)(Y2b + i);
  int c = i & 127;
  float4 a = *(const float4*)(AB + c);
  float4 b = *(const float4*)(AB + 128 + c);
  float4 o;
  o.x = fmaxf(fmaf(bflo2f(v.x), a.x, b.x), 0.f);
  o.y = fmaxf(fmaf(bfhi2f(v.x), a.y, b.y), 0.f);
  o.z = fmaxf(fmaf(bflo2f(v.y), a.z, b.z), 0.f);
  o.w = fmaxf(fmaf(bfhi2f(v.y), a.w, b.w), 0.f);
  *(float4*)(out + i) = o;
}

extern "C" void kernel_launch(void* const* d_in, const int* in_sizes, int n_in,
                              void* d_out, int out_size, void* d_ws, size_t ws_size,
                              hipStream_t stream){
  const float* h    = (const float*)d_in[0];
  const int*   esrc = (const int*)d_in[1];
  const int*   edst = (const int*)d_in[2];
  const float* W1   = (const float*)d_in[3];
  const float* b1   = (const float*)d_in[4];
  const float* g1   = (const float*)d_in[5];
  const float* be1  = (const float*)d_in[6];
  const float* W2   = (const float*)d_in[7];
  const float* b2   = (const float*)d_in[8];
  const float* g2   = (const float*)d_in[9];
  const float* be2  = (const float*)d_in[10];
  const float* eps  = (const float*)d_in[11];
  int n = in_sizes[0] / 128;
  int E = in_sizes[1];
  (void)n_in; (void)out_size; (void)ws_size;

  int NB = (n + 255) >> 8;
  int EB = (E + 4095) >> 12;
  int NG = (EB > NB) ? EB : NB;

  char* ws = (char*)d_ws;
  size_t off = 0;
  auto alloc = [&](size_t bytes) -> void* {
    void* p = ws + off;
    off += (bytes + 511) & ~(size_t)511;
    return p;
  };
  size_t feat_b = (size_t)n * 128 * 2;
  uint16_t* B1   = (uint16_t*)alloc(feat_b);        // hb  -> Y1b
  uint16_t* B2   = (uint16_t*)alloc(feat_b);        // binned -> Xb -> Y2b
  int*   row_off = (int*)alloc((size_t)(n + 1) * 4);
  int*   col_idx = (int*)alloc((size_t)E * 4);
  int*   M       = (int*)alloc((size_t)EB * NB * 4);
  int*   btot    = (int*)alloc((size_t)(NB + 1) * 4);
  int*   bbase   = (int*)alloc((size_t)(NB + 1) * 4);
  float* stats   = (float*)alloc(512 * 4);
  int*   bar     = (int*)alloc(64 * 4);
  float* AB1     = (float*)alloc(256 * 4);   // unused (kept for ws layout stability)
  uint16_t* Wt1  = (uint16_t*)alloc(128 * 128 * 2);
  uint16_t* Wt2  = (uint16_t*)alloc(128 * 128 * 2);
  (void)AB1;
  float* sum1 = stats;        float* sq1 = stats + 128;
  float* sum2 = stats + 256;  float* sq2 = stats + 384;
  uint16_t* hb  = B1;
  uint2*   binned = (uint2*)B2;
  uint16_t* Xb  = B2;
  uint16_t* Y1b = B1;
  uint16_t* Y2b = B2;

  int total = n * 128;
  int hblocks = total / 8 / 256;
  float invN = 1.0f / (float)n;

  k_prep<<<hblocks + 16, 256, 0, stream>>>(h, hb, hblocks, W1, W2, Wt1, Wt2, stats, bar);

  k_csr_all<<<NG, 256, 0, stream>>>(esrc, edst, M, btot, bbase, row_off, col_idx,
                                    binned, bar, E, n, NB, EB, NG);

  k_gather<<<(n + 3) / 4, 256, 0, stream>>>(hb, row_off, col_idx, eps, Xb, n);

  int gblocks = (n + 63) / 64;
  k_mgemm<false><<<gblocks, 256, 0, stream>>>(Xb, Wt1, b1,
      nullptr, nullptr, nullptr, nullptr, 0.f, Y1b, sum1, sq1, n);
  k_mgemm<true> <<<gblocks, 256, 0, stream>>>(Y1b, Wt2, b2,
      sum1, sq1, g1, be1, invN, Y2b, sum2, sq2, n);

  k_final<<<(total / 4 + 255) / 256, 256, 0, stream>>>(Y2b, sum2, sq2, g2, be2, invN,
                                                       (float*)d_out, total);
}

// Round 7
// 354.358 us; speedup vs baseline: 1.4875x; 1.4875x over previous
//
#include <hip/hip_runtime.h>
#include <hip/hip_bf16.h>
#include <stdint.h>

#define BN_EPS 1e-5f

typedef __attribute__((ext_vector_type(8)))  short bf16x8;
typedef __attribute__((ext_vector_type(16))) float f32x16;

static __device__ __forceinline__ float bflo2f(uint32_t p){
  union { uint32_t u; float f; } c; c.u = p << 16; return c.f;
}
static __device__ __forceinline__ float bfhi2f(uint32_t p){
  union { uint32_t u; float f; } c; c.u = p & 0xffff0000u; return c.f;
}
static __device__ __forceinline__ uint16_t f2bf(float f){
  union { float f; uint32_t u; } c; c.f = f;
  uint32_t u = c.u;
  return (uint16_t)((u + 0x7fffu + ((u >> 16) & 1u)) >> 16);
}
static __device__ __forceinline__ uint32_t pack2(float a, float b){
  return (uint32_t)f2bf(a) | ((uint32_t)f2bf(b) << 16);
}

// ---- prepass: h fp32->bf16  |  W transpose+swizzle  |  zero stats  |  per-chunk dst histogram ----
__global__ void k_prep(const float* __restrict__ h, uint16_t* __restrict__ hb, int hblocks,
                       const float* __restrict__ W1, const float* __restrict__ W2,
                       uint16_t* __restrict__ Wt1, uint16_t* __restrict__ Wt2,
                       float* __restrict__ stats,
                       const int* __restrict__ dst, int* __restrict__ M, int E, int NB){
  int b = blockIdx.x, t = threadIdx.x;
  if (b < hblocks){
    int i = (b * 256 + t) * 8;
    float4 a = *(const float4*)(h + i);
    float4 bb = *(const float4*)(h + i + 4);
    uint4 o;
    o.x = pack2(a.x, a.y); o.y = pack2(a.z, a.w);
    o.z = pack2(bb.x, bb.y); o.w = pack2(bb.z, bb.w);
    *(uint4*)(hb + i) = o;
    return;
  }
  if (b < hblocks + 16){
    if (b == hblocks && t < 128){
      float4 z = make_float4(0.f, 0.f, 0.f, 0.f);
      *(float4*)(stats + t * 4) = z;
    }
    int gid = (b - hblocks) * 256 + t;
    if (gid >= 4096) return;
    const float* Wf = (gid < 2048) ? W1 : W2;
    uint16_t* Wt = (gid < 2048) ? Wt1 : Wt2;
    int cid = gid & 2047;
    int nrow = cid >> 4;
    int c    = cid & 15;
    int k0 = c * 8;
    float e[8];
    #pragma unroll
    for (int j = 0; j < 8; ++j) e[j] = Wf[(k0 + j) * 128 + nrow];
    uint4 o;
    o.x = pack2(e[0], e[1]); o.y = pack2(e[2], e[3]);
    o.z = pack2(e[4], e[5]); o.w = pack2(e[6], e[7]);
    int cs = c ^ (nrow & 15);
    *(uint4*)(Wt + nrow * 128 + cs * 8) = o;
    return;
  }
  // histogram chunk
  int eb = b - hblocks - 16;
  __shared__ int cnt[512];
  cnt[t] = 0; cnt[t + 256] = 0;
  __syncthreads();
  int base = eb * 4096;
  #pragma unroll 4
  for (int j = t; j < 4096; j += 256){
    int i = base + j;
    if (i < E) atomicAdd(&cnt[dst[i] >> 8], 1);
  }
  __syncthreads();
  size_t row = (size_t)eb * NB;
  if (t < NB) M[row + t] = cnt[t];
  int t2 = t + 256;
  if (t2 < NB) M[row + t2] = cnt[t2];
}

// ---------------- CSR chain ----------------
__global__ void k_colscan(int* __restrict__ M, int* __restrict__ btot, int EB, int NB){
  __shared__ int s[256];
  int b = blockIdx.x, t = threadIdx.x;
  int i0 = 2 * t, i1 = 2 * t + 1;
  int v0 = (i0 < EB) ? M[(size_t)i0 * NB + b] : 0;
  int v1 = (i1 < EB) ? M[(size_t)i1 * NB + b] : 0;
  s[t] = v0 + v1;
  __syncthreads();
  for (int off = 1; off < 256; off <<= 1){
    int v = (t >= off) ? s[t - off] : 0;
    __syncthreads();
    s[t] += v;
    __syncthreads();
  }
  int excl = s[t] - (v0 + v1);
  if (i0 < EB) M[(size_t)i0 * NB + b] = excl;
  if (i1 < EB) M[(size_t)i1 * NB + b] = excl + v0;
  if (t == 255) btot[b] = s[255];
}

__global__ void k_bscan(const int* __restrict__ btot, int* __restrict__ bbase,
                        int* __restrict__ row_off, int NB, int n, int E){
  __shared__ int s[256];
  int t = threadIdx.x;
  int i0 = 2 * t, i1 = 2 * t + 1;
  int v0 = (i0 < NB) ? btot[i0] : 0;
  int v1 = (i1 < NB) ? btot[i1] : 0;
  s[t] = v0 + v1;
  __syncthreads();
  for (int off = 1; off < 256; off <<= 1){
    int v = (t >= off) ? s[t - off] : 0;
    __syncthreads();
    s[t] += v;
    __syncthreads();
  }
  int excl = s[t] - (v0 + v1);
  if (i0 < NB) bbase[i0] = excl;
  if (i1 < NB) bbase[i1] = excl + v0;
  if (t == 0){ bbase[NB] = E; row_off[n] = E; }
}

__global__ void k_bin(const int* __restrict__ src, const int* __restrict__ dst,
                      const int* __restrict__ M, const int* __restrict__ bbase,
                      uint2* __restrict__ binned, int E, int NB){
  __shared__ int comb[512];
  __shared__ int cur[512];
  int t = threadIdx.x;
  size_t row = (size_t)blockIdx.x * NB;
  if (t < NB) comb[t] = bbase[t] + M[row + t];
  int t2 = t + 256;
  if (t2 < NB) comb[t2] = bbase[t2] + M[row + t2];
  cur[t] = 0; cur[t + 256] = 0;
  __syncthreads();
  int base = blockIdx.x * 4096;
  #pragma unroll 4
  for (int j = t; j < 4096; j += 256){
    int i = base + j;
    if (i < E){
      int d = dst[i];
      int b = d >> 8;
      int r = atomicAdd(&cur[b], 1);
      binned[comb[b] + r] = make_uint2((unsigned)src[i], (unsigned)d);
    }
  }
}

__global__ void k_csr(const uint2* __restrict__ binned, const int* __restrict__ bbase,
                      int* __restrict__ row_off, int* __restrict__ col_idx, int n){
  __shared__ int cnt[256];
  __shared__ int off[256];
  __shared__ int cur[256];
  int b = blockIdx.x, t = threadIdx.x;
  int e0 = bbase[b], e1 = bbase[b + 1];
  int nb0 = b << 8;
  cnt[t] = 0; cur[t] = 0;
  __syncthreads();
  int m = e1 - e0;
  for (int j = t; j < m; j += 256) atomicAdd(&cnt[binned[e0 + j].y & 255], 1);
  __syncthreads();
  int v = cnt[t];
  off[t] = v;
  __syncthreads();
  for (int o = 1; o < 256; o <<= 1){
    int u = (t >= o) ? off[t - o] : 0;
    __syncthreads();
    off[t] += u;
    __syncthreads();
  }
  int excl = off[t] - v;
  __syncthreads();
  off[t] = excl;
  if (nb0 + t < n) row_off[nb0 + t] = e0 + excl;
  __syncthreads();
  for (int j = t; j < m; j += 256){
    uint2 p = binned[e0 + j];
    int dl = p.y & 255;
    int r = atomicAdd(&cur[dl], 1);
    col_idx[e0 + off[dl] + r] = (int)p.x;
  }
}

// -------- gather: 16 lanes per row (16B/lane), up to 16 neighbors in flight --------
__global__ void k_gather(const uint16_t* __restrict__ hb, const int* __restrict__ row_off,
                         const int* __restrict__ col_idx, const float* __restrict__ eps_p,
                         uint16_t* __restrict__ Xb, int n){
  int node = (blockIdx.x << 2) + (threadIdx.x >> 6);
  int lane = threadIdx.x & 63;
  if (node >= n) return;
  int g = lane >> 4;
  int c = lane & 15;
  const uint4* hp4 = (const uint4*)hb;
  int j = row_off[node], jend = row_off[node + 1];
  float a0=0.f,a1=0.f,a2=0.f,a3=0.f,a4=0.f,a5=0.f,a6=0.f,a7=0.f;
  for (; j + 16 <= jend; j += 16){
    int sA = col_idx[j + g];
    int sB = col_idx[j + 4 + g];
    int sC = col_idx[j + 8 + g];
    int sD = col_idx[j + 12 + g];
    uint4 vA = hp4[(size_t)sA * 16 + c];
    uint4 vB = hp4[(size_t)sB * 16 + c];
    uint4 vC = hp4[(size_t)sC * 16 + c];
    uint4 vD = hp4[(size_t)sD * 16 + c];
    a0 += (bflo2f(vA.x) + bflo2f(vB.x)) + (bflo2f(vC.x) + bflo2f(vD.x));
    a1 += (bfhi2f(vA.x) + bfhi2f(vB.x)) + (bfhi2f(vC.x) + bfhi2f(vD.x));
    a2 += (bflo2f(vA.y) + bflo2f(vB.y)) + (bflo2f(vC.y) + bflo2f(vD.y));
    a3 += (bfhi2f(vA.y) + bfhi2f(vB.y)) + (bfhi2f(vC.y) + bfhi2f(vD.y));
    a4 += (bflo2f(vA.z) + bflo2f(vB.z)) + (bflo2f(vC.z) + bflo2f(vD.z));
    a5 += (bfhi2f(vA.z) + bfhi2f(vB.z)) + (bfhi2f(vC.z) + bfhi2f(vD.z));
    a6 += (bflo2f(vA.w) + bflo2f(vB.w)) + (bflo2f(vC.w) + bflo2f(vD.w));
    a7 += (bfhi2f(vA.w) + bfhi2f(vB.w)) + (bfhi2f(vC.w) + bfhi2f(vD.w));
  }
  for (; j + 8 <= jend; j += 8){
    int sA = col_idx[j + g];
    int sB = col_idx[j + 4 + g];
    uint4 vA = hp4[(size_t)sA * 16 + c];
    uint4 vB = hp4[(size_t)sB * 16 + c];
    a0 += bflo2f(vA.x) + bflo2f(vB.x);
    a1 += bfhi2f(vA.x) + bfhi2f(vB.x);
    a2 += bflo2f(vA.y) + bflo2f(vB.y);
    a3 += bfhi2f(vA.y) + bfhi2f(vB.y);
    a4 += bflo2f(vA.z) + bflo2f(vB.z);
    a5 += bfhi2f(vA.z) + bfhi2f(vB.z);
    a6 += bflo2f(vA.w) + bflo2f(vB.w);
    a7 += bfhi2f(vA.w) + bfhi2f(vB.w);
  }
  for (; j + 4 <= jend; j += 4){
    int s = col_idx[j + g];
    uint4 v = hp4[(size_t)s * 16 + c];
    a0 += bflo2f(v.x); a1 += bfhi2f(v.x);
    a2 += bflo2f(v.y); a3 += bfhi2f(v.y);
    a4 += bflo2f(v.z); a5 += bfhi2f(v.z);
    a6 += bflo2f(v.w); a7 += bfhi2f(v.w);
  }
  int rem = jend - j;
  if (rem > 0){
    int jj = j + (g < rem ? g : rem - 1);
    float w = (g < rem) ? 1.f : 0.f;
    int s = col_idx[jj];
    uint4 v = hp4[(size_t)s * 16 + c];
    a0 = fmaf(w, bflo2f(v.x), a0); a1 = fmaf(w, bfhi2f(v.x), a1);
    a2 = fmaf(w, bflo2f(v.y), a2); a3 = fmaf(w, bfhi2f(v.y), a3);
    a4 = fmaf(w, bflo2f(v.z), a4); a5 = fmaf(w, bfhi2f(v.z), a5);
    a6 = fmaf(w, bflo2f(v.w), a6); a7 = fmaf(w, bfhi2f(v.w), a7);
  }
  a0 += __shfl_xor(a0, 16); a1 += __shfl_xor(a1, 16);
  a2 += __shfl_xor(a2, 16); a3 += __shfl_xor(a3, 16);
  a4 += __shfl_xor(a4, 16); a5 += __shfl_xor(a5, 16);
  a6 += __shfl_xor(a6, 16); a7 += __shfl_xor(a7, 16);
  a0 += __shfl_xor(a0, 32); a1 += __shfl_xor(a1, 32);
  a2 += __shfl_xor(a2, 32); a3 += __shfl_xor(a3, 32);
  a4 += __shfl_xor(a4, 32); a5 += __shfl_xor(a5, 32);
  a6 += __shfl_xor(a6, 32); a7 += __shfl_xor(a7, 32);
  if (g == 0){
    float ce = 1.0f + eps_p[0];
    uint4 vh = hp4[(size_t)node * 16 + c];
    a0 = fmaf(ce, bflo2f(vh.x), a0); a1 = fmaf(ce, bfhi2f(vh.x), a1);
    a2 = fmaf(ce, bflo2f(vh.y), a2); a3 = fmaf(ce, bfhi2f(vh.y), a3);
    a4 = fmaf(ce, bflo2f(vh.z), a4); a5 = fmaf(ce, bfhi2f(vh.z), a5);
    a6 = fmaf(ce, bflo2f(vh.w), a6); a7 = fmaf(ce, bfhi2f(vh.w), a7);
    uint4 o;
    o.x = pack2(a0, a1); o.y = pack2(a2, a3);
    o.z = pack2(a4, a5); o.w = pack2(a6, a7);
    *((uint4*)Xb + (size_t)node * 16 + c) = o;
  }
}

// -------- MFMA GEMM; BN_IN computes BN coefs in-kernel from previous layer's sums --------
template<bool BN_IN>
__global__ __launch_bounds__(256, 3) void k_mgemm(
    const uint16_t* __restrict__ Ag, const uint16_t* __restrict__ Wt,
    const float* __restrict__ bias_f,
    const float* __restrict__ sin, const float* __restrict__ sqin,
    const float* __restrict__ gin, const float* __restrict__ bein, float invN,
    uint16_t* __restrict__ Yout, float* __restrict__ osum, float* __restrict__ osq, int n){
  __shared__ __align__(16) uint16_t Al[64 * 128];
  __shared__ __align__(16) uint16_t Wl[128 * 128];
  __shared__ float csum[128], csq[128];
  __shared__ __align__(16) float ABl[256];
  int tid = threadIdx.x;
  int rbase = blockIdx.x * 64;

  if (BN_IN){
    if (tid < 128){
      float mu = sin[tid] * invN;
      float var = sqin[tid] * invN - mu * mu;
      float A = gin[tid] * rsqrtf(var + BN_EPS);
      ABl[tid] = A;
      ABl[128 + tid] = bein[tid] - mu * A;
    }
    __syncthreads();
  }

  {
    const uint4* g = (const uint4*)Wt;
    uint4* d = (uint4*)Wl;
    #pragma unroll
    for (int i = 0; i < 8; ++i) d[tid + 256 * i] = g[tid + 256 * i];
  }
  #pragma unroll
  for (int i = 0; i < 4; ++i){
    int f = tid + 256 * i;
    int m = f >> 4, c = f & 15;
    int gr = rbase + m;
    uint4 v = make_uint4(0, 0, 0, 0);
    if (gr < n){
      v = *(const uint4*)(Ag + (size_t)gr * 128 + c * 8);
      if (BN_IN){
        int k0 = c * 8;
        float4 ka0 = *(const float4*)(ABl + k0);
        float4 ka1 = *(const float4*)(ABl + k0 + 4);
        float4 kb0 = *(const float4*)(ABl + 128 + k0);
        float4 kb1 = *(const float4*)(ABl + 128 + k0 + 4);
        float e0 = fmaxf(fmaf(bflo2f(v.x), ka0.x, kb0.x), 0.f);
        float e1 = fmaxf(fmaf(bfhi2f(v.x), ka0.y, kb0.y), 0.f);
        float e2 = fmaxf(fmaf(bflo2f(v.y), ka0.z, kb0.z), 0.f);
        float e3 = fmaxf(fmaf(bfhi2f(v.y), ka0.w, kb0.w), 0.f);
        float e4 = fmaxf(fmaf(bflo2f(v.z), ka1.x, kb1.x), 0.f);
        float e5 = fmaxf(fmaf(bfhi2f(v.z), ka1.y, kb1.y), 0.f);
        float e6 = fmaxf(fmaf(bflo2f(v.w), ka1.z, kb1.z), 0.f);
        float e7 = fmaxf(fmaf(bfhi2f(v.w), ka1.w, kb1.w), 0.f);
        v.x = pack2(e0, e1); v.y = pack2(e2, e3);
        v.z = pack2(e4, e5); v.w = pack2(e6, e7);
      }
    }
    *(uint4*)((char*)Al + m * 256 + ((c ^ (m & 15)) * 16)) = v;
  }
  if (tid < 128){ csum[tid] = 0.f; csq[tid] = 0.f; }
  __syncthreads();

  int lane = tid & 63;
  int w    = tid >> 6;
  int hi   = lane >> 5;
  int key  = lane & 15;
  int m0   = (w & 1) * 32;
  int n0   = (w >> 1) * 64;
  int mrow = m0 + (lane & 31);
  int nrow0 = n0 + (lane & 31);
  int nrow1 = nrow0 + 32;

  f32x16 acc0, acc1;
  #pragma unroll
  for (int i = 0; i < 16; ++i){ acc0[i] = 0.f; acc1[i] = 0.f; }

  const char* Ab = (const char*)Al;
  const char* Wb = (const char*)Wl;
  #pragma unroll
  for (int kt = 0; kt < 8; ++kt){
    int cs = ((2 * kt + hi) ^ key) * 16;
    bf16x8 a  = *(const bf16x8*)(Ab + mrow  * 256 + cs);
    bf16x8 b0 = *(const bf16x8*)(Wb + nrow0 * 256 + cs);
    bf16x8 b1 = *(const bf16x8*)(Wb + nrow1 * 256 + cs);
    acc0 = __builtin_amdgcn_mfma_f32_32x32x16_bf16(a, b0, acc0, 0, 0, 0);
    acc1 = __builtin_amdgcn_mfma_f32_32x32x16_bf16(a, b1, acc1, 0, 0, 0);
  }
  __syncthreads();

  uint16_t* Yl = Wl;
  float bias0 = bias_f[nrow0];
  float bias1 = bias_f[nrow1];
  float ps0 = 0.f, pq0 = 0.f, ps1 = 0.f, pq1 = 0.f;
  #pragma unroll
  for (int r = 0; r < 16; ++r){
    int row = m0 + (r & 3) + 8 * (r >> 2) + 4 * hi;
    bool valid = (rbase + row) < n;
    float y0 = acc0[r] + bias0;
    float y1 = acc1[r] + bias1;
    if (valid){
      ps0 += y0; pq0 += y0 * y0;
      ps1 += y1; pq1 += y1 * y1;
    }
    Yl[row * 128 + nrow0] = f2bf(y0);
    Yl[row * 128 + nrow1] = f2bf(y1);
  }
  atomicAdd(&csum[nrow0], ps0); atomicAdd(&csq[nrow0], pq0);
  atomicAdd(&csum[nrow1], ps1); atomicAdd(&csq[nrow1], pq1);
  __syncthreads();

  #pragma unroll
  for (int i = 0; i < 4; ++i){
    int id = tid + 256 * i;
    int row = id >> 4, c = id & 15;
    int gr = rbase + row;
    if (gr < n)
      *((uint4*)Yout + (size_t)gr * 16 + c) = *((const uint4*)Yl + id);
  }
  if (tid < 128){
    atomicAdd(&osum[tid], csum[tid]);
    atomicAdd(&osq[tid], csq[tid]);
  }
}

// -------- final: BN2 coefs computed per-block, then BN+ReLU, fp32 out --------
__global__ void k_final(const uint16_t* __restrict__ Y2b,
                        const float* __restrict__ sum2, const float* __restrict__ sq2,
                        const float* __restrict__ g2, const float* __restrict__ be2, float invN,
                        float* __restrict__ out, int total){
  __shared__ __align__(16) float AB[256];
  int tid = threadIdx.x;
  if (tid < 128){
    float mu = sum2[tid] * invN;
    float var = sq2[tid] * invN - mu * mu;
    float A = g2[tid] * rsqrtf(var + BN_EPS);
    AB[tid] = A;
    AB[128 + tid] = be2[tid] - mu * A;
  }
  __syncthreads();
  int i = (blockIdx.x * 256 + tid) * 4;
  if (i >= total) return;
  uint2 v = *(const uint2*)(Y2b + i);
  int c = i & 127;
  float4 a = *(const float4*)(AB + c);
  float4 b = *(const float4*)(AB + 128 + c);
  float4 o;
  o.x = fmaxf(fmaf(bflo2f(v.x), a.x, b.x), 0.f);
  o.y = fmaxf(fmaf(bfhi2f(v.x), a.y, b.y), 0.f);
  o.z = fmaxf(fmaf(bflo2f(v.y), a.z, b.z), 0.f);
  o.w = fmaxf(fmaf(bfhi2f(v.y), a.w, b.w), 0.f);
  *(float4*)(out + i) = o;
}

extern "C" void kernel_launch(void* const* d_in, const int* in_sizes, int n_in,
                              void* d_out, int out_size, void* d_ws, size_t ws_size,
                              hipStream_t stream){
  const float* h    = (const float*)d_in[0];
  const int*   esrc = (const int*)d_in[1];
  const int*   edst = (const int*)d_in[2];
  const float* W1   = (const float*)d_in[3];
  const float* b1   = (const float*)d_in[4];
  const float* g1   = (const float*)d_in[5];
  const float* be1  = (const float*)d_in[6];
  const float* W2   = (const float*)d_in[7];
  const float* b2   = (const float*)d_in[8];
  const float* g2   = (const float*)d_in[9];
  const float* be2  = (const float*)d_in[10];
  const float* eps  = (const float*)d_in[11];
  int n = in_sizes[0] / 128;
  int E = in_sizes[1];
  (void)n_in; (void)out_size; (void)ws_size;

  int NB = (n + 255) >> 8;
  int EB = (E + 4095) >> 12;

  char* ws = (char*)d_ws;
  size_t off = 0;
  auto alloc = [&](size_t bytes) -> void* {
    void* p = ws + off;
    off += (bytes + 511) & ~(size_t)511;
    return p;
  };
  size_t feat_b = (size_t)n * 128 * 2;
  uint16_t* B1   = (uint16_t*)alloc(feat_b);        // hb  -> Y1b
  uint16_t* B2   = (uint16_t*)alloc(feat_b);        // binned -> Xb -> Y2b
  int*   row_off = (int*)alloc((size_t)(n + 1) * 4);
  int*   col_idx = (int*)alloc((size_t)E * 4);
  int*   M       = (int*)alloc((size_t)EB * NB * 4);
  int*   btot    = (int*)alloc((size_t)(NB + 1) * 4);
  int*   bbase   = (int*)alloc((size_t)(NB + 1) * 4);
  float* stats   = (float*)alloc(512 * 4);
  uint16_t* Wt1  = (uint16_t*)alloc(128 * 128 * 2);
  uint16_t* Wt2  = (uint16_t*)alloc(128 * 128 * 2);
  float* sum1 = stats;        float* sq1 = stats + 128;
  float* sum2 = stats + 256;  float* sq2 = stats + 384;
  uint16_t* hb  = B1;
  uint2*   binned = (uint2*)B2;
  uint16_t* Xb  = B2;
  uint16_t* Y1b = B1;
  uint16_t* Y2b = B2;

  int total = n * 128;
  int hblocks = total / 8 / 256;
  float invN = 1.0f / (float)n;

  k_prep<<<hblocks + 16 + EB, 256, 0, stream>>>(h, hb, hblocks, W1, W2, Wt1, Wt2,
                                                stats, edst, M, E, NB);
  k_colscan<<<NB, 256, 0, stream>>>(M, btot, EB, NB);
  k_bscan  <<<1, 256, 0, stream>>>(btot, bbase, row_off, NB, n, E);
  k_bin    <<<EB, 256, 0, stream>>>(esrc, edst, M, bbase, binned, E, NB);
  k_csr    <<<NB, 256, 0, stream>>>(binned, bbase, row_off, col_idx, n);

  k_gather<<<(n + 3) / 4, 256, 0, stream>>>(hb, row_off, col_idx, eps, Xb, n);

  int gblocks = (n + 63) / 64;
  k_mgemm<false><<<gblocks, 256, 0, stream>>>(Xb, Wt1, b1,
      nullptr, nullptr, nullptr, nullptr, 0.f, Y1b, sum1, sq1, n);
  k_mgemm<true> <<<gblocks, 256, 0, stream>>>(Y1b, Wt2, b2,
      sum1, sq1, g1, be1, invN, Y2b, sum2, sq2, n);

  k_final<<<(total / 4 + 255) / 256, 256, 0, stream>>>(Y2b, sum2, sq2, g2, be2, invN,
                                                       (float*)d_out, total);
}

// Round 8
// 309.923 us; speedup vs baseline: 1.7008x; 1.1434x over previous
//
#include <hip/hip_runtime.h>
#include <hip/hip_bf16.h>
#include <stdint.h>

#define BN_EPS 1e-5f
#define NSTRIPE 64

typedef __attribute__((ext_vector_type(8)))  short bf16x8;
typedef __attribute__((ext_vector_type(16))) float f32x16;

static __device__ __forceinline__ float bflo2f(uint32_t p){
  union { uint32_t u; float f; } c; c.u = p << 16; return c.f;
}
static __device__ __forceinline__ float bfhi2f(uint32_t p){
  union { uint32_t u; float f; } c; c.u = p & 0xffff0000u; return c.f;
}
static __device__ __forceinline__ uint16_t f2bf(float f){
  union { float f; uint32_t u; } c; c.f = f;
  uint32_t u = c.u;
  return (uint16_t)((u + 0x7fffu + ((u >> 16) & 1u)) >> 16);
}
static __device__ __forceinline__ uint32_t pack2(float a, float b){
  return (uint32_t)f2bf(a) | ((uint32_t)f2bf(b) << 16);
}

// ---- prepass: h fp32->bf16 | W transpose+swizzle | zero striped stats | per-chunk dst histogram ----
__global__ void k_prep(const float* __restrict__ h, uint16_t* __restrict__ hb, int hblocks,
                       const float* __restrict__ W1, const float* __restrict__ W2,
                       uint16_t* __restrict__ Wt1, uint16_t* __restrict__ Wt2,
                       float* __restrict__ stats,
                       const int* __restrict__ dst, int* __restrict__ M, int E, int NB){
  int b = blockIdx.x, t = threadIdx.x;
  if (b < hblocks){
    int i = (b * 256 + t) * 8;
    float4 a = *(const float4*)(h + i);
    float4 bb = *(const float4*)(h + i + 4);
    uint4 o;
    o.x = pack2(a.x, a.y); o.y = pack2(a.z, a.w);
    o.z = pack2(bb.x, bb.y); o.w = pack2(bb.z, bb.w);
    *(uint4*)(hb + i) = o;
    return;
  }
  if (b < hblocks + 16){
    int gid = (b - hblocks) * 256 + t;   // 0..4095
    { // zero striped stats: 4 arrays * 64 stripes * 128 cols = 32768 floats
      float4 z = make_float4(0.f, 0.f, 0.f, 0.f);
      *(float4*)(stats + gid * 8) = z;
      *(float4*)(stats + gid * 8 + 4) = z;
    }
    const float* Wf = (gid < 2048) ? W1 : W2;
    uint16_t* Wt = (gid < 2048) ? Wt1 : Wt2;
    int cid = gid & 2047;
    int nrow = cid >> 4;
    int c    = cid & 15;
    int k0 = c * 8;
    float e[8];
    #pragma unroll
    for (int j = 0; j < 8; ++j) e[j] = Wf[(k0 + j) * 128 + nrow];
    uint4 o;
    o.x = pack2(e[0], e[1]); o.y = pack2(e[2], e[3]);
    o.z = pack2(e[4], e[5]); o.w = pack2(e[6], e[7]);
    int cs = c ^ (nrow & 15);
    *(uint4*)(Wt + nrow * 128 + cs * 8) = o;
    return;
  }
  // histogram chunk
  int eb = b - hblocks - 16;
  __shared__ int cnt[512];
  cnt[t] = 0; cnt[t + 256] = 0;
  __syncthreads();
  int base = eb * 4096;
  #pragma unroll 4
  for (int j = t; j < 4096; j += 256){
    int i = base + j;
    if (i < E) atomicAdd(&cnt[dst[i] >> 8], 1);
  }
  __syncthreads();
  size_t row = (size_t)eb * NB;
  if (t < NB) M[row + t] = cnt[t];
  int t2 = t + 256;
  if (t2 < NB) M[row + t2] = cnt[t2];
}

// ---------------- CSR chain ----------------
__global__ void k_colscan(int* __restrict__ M, int* __restrict__ btot, int EB, int NB){
  __shared__ int s[256];
  int b = blockIdx.x, t = threadIdx.x;
  int i0 = 2 * t, i1 = 2 * t + 1;
  int v0 = (i0 < EB) ? M[(size_t)i0 * NB + b] : 0;
  int v1 = (i1 < EB) ? M[(size_t)i1 * NB + b] : 0;
  s[t] = v0 + v1;
  __syncthreads();
  for (int off = 1; off < 256; off <<= 1){
    int v = (t >= off) ? s[t - off] : 0;
    __syncthreads();
    s[t] += v;
    __syncthreads();
  }
  int excl = s[t] - (v0 + v1);
  if (i0 < EB) M[(size_t)i0 * NB + b] = excl;
  if (i1 < EB) M[(size_t)i1 * NB + b] = excl + v0;
  if (t == 255) btot[b] = s[255];
}

__global__ void k_bscan(const int* __restrict__ btot, int* __restrict__ bbase,
                        int* __restrict__ row_off, int NB, int n, int E){
  __shared__ int s[256];
  int t = threadIdx.x;
  int i0 = 2 * t, i1 = 2 * t + 1;
  int v0 = (i0 < NB) ? btot[i0] : 0;
  int v1 = (i1 < NB) ? btot[i1] : 0;
  s[t] = v0 + v1;
  __syncthreads();
  for (int off = 1; off < 256; off <<= 1){
    int v = (t >= off) ? s[t - off] : 0;
    __syncthreads();
    s[t] += v;
    __syncthreads();
  }
  int excl = s[t] - (v0 + v1);
  if (i0 < NB) bbase[i0] = excl;
  if (i1 < NB) bbase[i1] = excl + v0;
  if (t == 0){ bbase[NB] = E; row_off[n] = E; }
}

__global__ void k_bin(const int* __restrict__ src, const int* __restrict__ dst,
                      const int* __restrict__ M, const int* __restrict__ bbase,
                      uint2* __restrict__ binned, int E, int NB){
  __shared__ int comb[512];
  __shared__ int cur[512];
  int t = threadIdx.x;
  size_t row = (size_t)blockIdx.x * NB;
  if (t < NB) comb[t] = bbase[t] + M[row + t];
  int t2 = t + 256;
  if (t2 < NB) comb[t2] = bbase[t2] + M[row + t2];
  cur[t] = 0; cur[t + 256] = 0;
  __syncthreads();
  int base = blockIdx.x * 4096;
  #pragma unroll 4
  for (int j = t; j < 4096; j += 256){
    int i = base + j;
    if (i < E){
      int d = dst[i];
      int b = d >> 8;
      int r = atomicAdd(&cur[b], 1);
      binned[comb[b] + r] = make_uint2((unsigned)src[i], (unsigned)d);
    }
  }
}

__global__ void k_csr(const uint2* __restrict__ binned, const int* __restrict__ bbase,
                      int* __restrict__ row_off, int* __restrict__ col_idx, int n){
  __shared__ int cnt[256];
  __shared__ int off[256];
  __shared__ int cur[256];
  int b = blockIdx.x, t = threadIdx.x;
  int e0 = bbase[b], e1 = bbase[b + 1];
  int nb0 = b << 8;
  cnt[t] = 0; cur[t] = 0;
  __syncthreads();
  int m = e1 - e0;
  for (int j = t; j < m; j += 256) atomicAdd(&cnt[binned[e0 + j].y & 255], 1);
  __syncthreads();
  int v = cnt[t];
  off[t] = v;
  __syncthreads();
  for (int o = 1; o < 256; o <<= 1){
    int u = (t >= o) ? off[t - o] : 0;
    __syncthreads();
    off[t] += u;
    __syncthreads();
  }
  int excl = off[t] - v;
  __syncthreads();
  off[t] = excl;
  if (nb0 + t < n) row_off[nb0 + t] = e0 + excl;
  __syncthreads();
  for (int j = t; j < m; j += 256){
    uint2 p = binned[e0 + j];
    int dl = p.y & 255;
    int r = atomicAdd(&cur[dl], 1);
    col_idx[e0 + off[dl] + r] = (int)p.x;
  }
}

// -------- gather: 16 lanes per row (16B/lane), up to 16 neighbors in flight --------
__global__ void k_gather(const uint16_t* __restrict__ hb, const int* __restrict__ row_off,
                         const int* __restrict__ col_idx, const float* __restrict__ eps_p,
                         uint16_t* __restrict__ Xb, int n){
  int node = (blockIdx.x << 2) + (threadIdx.x >> 6);
  int lane = threadIdx.x & 63;
  if (node >= n) return;
  int g = lane >> 4;
  int c = lane & 15;
  const uint4* hp4 = (const uint4*)hb;
  int j = row_off[node], jend = row_off[node + 1];
  float a0=0.f,a1=0.f,a2=0.f,a3=0.f,a4=0.f,a5=0.f,a6=0.f,a7=0.f;
  for (; j + 16 <= jend; j += 16){
    int sA = col_idx[j + g];
    int sB = col_idx[j + 4 + g];
    int sC = col_idx[j + 8 + g];
    int sD = col_idx[j + 12 + g];
    uint4 vA = hp4[(size_t)sA * 16 + c];
    uint4 vB = hp4[(size_t)sB * 16 + c];
    uint4 vC = hp4[(size_t)sC * 16 + c];
    uint4 vD = hp4[(size_t)sD * 16 + c];
    a0 += (bflo2f(vA.x) + bflo2f(vB.x)) + (bflo2f(vC.x) + bflo2f(vD.x));
    a1 += (bfhi2f(vA.x) + bfhi2f(vB.x)) + (bfhi2f(vC.x) + bfhi2f(vD.x));
    a2 += (bflo2f(vA.y) + bflo2f(vB.y)) + (bflo2f(vC.y) + bflo2f(vD.y));
    a3 += (bfhi2f(vA.y) + bfhi2f(vB.y)) + (bfhi2f(vC.y) + bfhi2f(vD.y));
    a4 += (bflo2f(vA.z) + bflo2f(vB.z)) + (bflo2f(vC.z) + bflo2f(vD.z));
    a5 += (bfhi2f(vA.z) + bfhi2f(vB.z)) + (bfhi2f(vC.z) + bfhi2f(vD.z));
    a6 += (bflo2f(vA.w) + bflo2f(vB.w)) + (bflo2f(vC.w) + bflo2f(vD.w));
    a7 += (bfhi2f(vA.w) + bfhi2f(vB.w)) + (bfhi2f(vC.w) + bfhi2f(vD.w));
  }
  for (; j + 8 <= jend; j += 8){
    int sA = col_idx[j + g];
    int sB = col_idx[j + 4 + g];
    uint4 vA = hp4[(size_t)sA * 16 + c];
    uint4 vB = hp4[(size_t)sB * 16 + c];
    a0 += bflo2f(vA.x) + bflo2f(vB.x);
    a1 += bfhi2f(vA.x) + bfhi2f(vB.x);
    a2 += bflo2f(vA.y) + bflo2f(vB.y);
    a3 += bfhi2f(vA.y) + bfhi2f(vB.y);
    a4 += bflo2f(vA.z) + bflo2f(vB.z);
    a5 += bfhi2f(vA.z) + bfhi2f(vB.z);
    a6 += bflo2f(vA.w) + bflo2f(vB.w);
    a7 += bfhi2f(vA.w) + bfhi2f(vB.w);
  }
  for (; j + 4 <= jend; j += 4){
    int s = col_idx[j + g];
    uint4 v = hp4[(size_t)s * 16 + c];
    a0 += bflo2f(v.x); a1 += bfhi2f(v.x);
    a2 += bflo2f(v.y); a3 += bfhi2f(v.y);
    a4 += bflo2f(v.z); a5 += bfhi2f(v.z);
    a6 += bflo2f(v.w); a7 += bfhi2f(v.w);
  }
  int rem = jend - j;
  if (rem > 0){
    int jj = j + (g < rem ? g : rem - 1);
    float w = (g < rem) ? 1.f : 0.f;
    int s = col_idx[jj];
    uint4 v = hp4[(size_t)s * 16 + c];
    a0 = fmaf(w, bflo2f(v.x), a0); a1 = fmaf(w, bfhi2f(v.x), a1);
    a2 = fmaf(w, bflo2f(v.y), a2); a3 = fmaf(w, bfhi2f(v.y), a3);
    a4 = fmaf(w, bflo2f(v.z), a4); a5 = fmaf(w, bfhi2f(v.z), a5);
    a6 = fmaf(w, bflo2f(v.w), a6); a7 = fmaf(w, bfhi2f(v.w), a7);
  }
  a0 += __shfl_xor(a0, 16); a1 += __shfl_xor(a1, 16);
  a2 += __shfl_xor(a2, 16); a3 += __shfl_xor(a3, 16);
  a4 += __shfl_xor(a4, 16); a5 += __shfl_xor(a5, 16);
  a6 += __shfl_xor(a6, 16); a7 += __shfl_xor(a7, 16);
  a0 += __shfl_xor(a0, 32); a1 += __shfl_xor(a1, 32);
  a2 += __shfl_xor(a2, 32); a3 += __shfl_xor(a3, 32);
  a4 += __shfl_xor(a4, 32); a5 += __shfl_xor(a5, 32);
  a6 += __shfl_xor(a6, 32); a7 += __shfl_xor(a7, 32);
  if (g == 0){
    float ce = 1.0f + eps_p[0];
    uint4 vh = hp4[(size_t)node * 16 + c];
    a0 = fmaf(ce, bflo2f(vh.x), a0); a1 = fmaf(ce, bfhi2f(vh.x), a1);
    a2 = fmaf(ce, bflo2f(vh.y), a2); a3 = fmaf(ce, bfhi2f(vh.y), a3);
    a4 = fmaf(ce, bflo2f(vh.z), a4); a5 = fmaf(ce, bfhi2f(vh.z), a5);
    a6 = fmaf(ce, bflo2f(vh.w), a6); a7 = fmaf(ce, bfhi2f(vh.w), a7);
    uint4 o;
    o.x = pack2(a0, a1); o.y = pack2(a2, a3);
    o.z = pack2(a4, a5); o.w = pack2(a6, a7);
    *((uint4*)Xb + (size_t)node * 16 + c) = o;
  }
}

// -------- MFMA GEMM; striped stats atomics (stripe = blockIdx & 63) --------
// BN_IN: reduces the 64 input stripes in-kernel to get BN coefs.
template<bool BN_IN>
__global__ __launch_bounds__(256, 3) void k_mgemm(
    const uint16_t* __restrict__ Ag, const uint16_t* __restrict__ Wt,
    const float* __restrict__ bias_f,
    const float* __restrict__ sin_s, const float* __restrict__ sqin_s,
    const float* __restrict__ gin, const float* __restrict__ bein, float invN,
    uint16_t* __restrict__ Yout, float* __restrict__ osum_s, float* __restrict__ osq_s, int n){
  __shared__ __align__(16) uint16_t Al[64 * 128];
  __shared__ __align__(16) uint16_t Wl[128 * 128];
  __shared__ float csum[128], csq[128];
  __shared__ __align__(16) float ABl[256];
  int tid = threadIdx.x;
  int rbase = blockIdx.x * 64;
  int stripe = blockIdx.x & (NSTRIPE - 1);

  if (BN_IN){
    if (tid < 128){
      float s = 0.f, q = 0.f;
      #pragma unroll 8
      for (int st = 0; st < NSTRIPE; ++st){
        s += sin_s[st * 128 + tid];
        q += sqin_s[st * 128 + tid];
      }
      float mu = s * invN;
      float var = q * invN - mu * mu;
      float A = gin[tid] * rsqrtf(var + BN_EPS);
      ABl[tid] = A;
      ABl[128 + tid] = bein[tid] - mu * A;
    }
    __syncthreads();
  }

  {
    const uint4* g = (const uint4*)Wt;
    uint4* d = (uint4*)Wl;
    #pragma unroll
    for (int i = 0; i < 8; ++i) d[tid + 256 * i] = g[tid + 256 * i];
  }
  #pragma unroll
  for (int i = 0; i < 4; ++i){
    int f = tid + 256 * i;
    int m = f >> 4, c = f & 15;
    int gr = rbase + m;
    uint4 v = make_uint4(0, 0, 0, 0);
    if (gr < n){
      v = *(const uint4*)(Ag + (size_t)gr * 128 + c * 8);
      if (BN_IN){
        int k0 = c * 8;
        float4 ka0 = *(const float4*)(ABl + k0);
        float4 ka1 = *(const float4*)(ABl + k0 + 4);
        float4 kb0 = *(const float4*)(ABl + 128 + k0);
        float4 kb1 = *(const float4*)(ABl + 128 + k0 + 4);
        float e0 = fmaxf(fmaf(bflo2f(v.x), ka0.x, kb0.x), 0.f);
        float e1 = fmaxf(fmaf(bfhi2f(v.x), ka0.y, kb0.y), 0.f);
        float e2 = fmaxf(fmaf(bflo2f(v.y), ka0.z, kb0.z), 0.f);
        float e3 = fmaxf(fmaf(bfhi2f(v.y), ka0.w, kb0.w), 0.f);
        float e4 = fmaxf(fmaf(bflo2f(v.z), ka1.x, kb1.x), 0.f);
        float e5 = fmaxf(fmaf(bfhi2f(v.z), ka1.y, kb1.y), 0.f);
        float e6 = fmaxf(fmaf(bflo2f(v.w), ka1.z, kb1.z), 0.f);
        float e7 = fmaxf(fmaf(bfhi2f(v.w), ka1.w, kb1.w), 0.f);
        v.x = pack2(e0, e1); v.y = pack2(e2, e3);
        v.z = pack2(e4, e5); v.w = pack2(e6, e7);
      }
    }
    *(uint4*)((char*)Al + m * 256 + ((c ^ (m & 15)) * 16)) = v;
  }
  if (tid < 128){ csum[tid] = 0.f; csq[tid] = 0.f; }
  __syncthreads();

  int lane = tid & 63;
  int w    = tid >> 6;
  int hi   = lane >> 5;
  int key  = lane & 15;
  int m0   = (w & 1) * 32;
  int n0   = (w >> 1) * 64;
  int mrow = m0 + (lane & 31);
  int nrow0 = n0 + (lane & 31);
  int nrow1 = nrow0 + 32;

  f32x16 acc0, acc1;
  #pragma unroll
  for (int i = 0; i < 16; ++i){ acc0[i] = 0.f; acc1[i] = 0.f; }

  const char* Ab = (const char*)Al;
  const char* Wb = (const char*)Wl;
  #pragma unroll
  for (int kt = 0; kt < 8; ++kt){
    int cs = ((2 * kt + hi) ^ key) * 16;
    bf16x8 a  = *(const bf16x8*)(Ab + mrow  * 256 + cs);
    bf16x8 b0 = *(const bf16x8*)(Wb + nrow0 * 256 + cs);
    bf16x8 b1 = *(const bf16x8*)(Wb + nrow1 * 256 + cs);
    acc0 = __builtin_amdgcn_mfma_f32_32x32x16_bf16(a, b0, acc0, 0, 0, 0);
    acc1 = __builtin_amdgcn_mfma_f32_32x32x16_bf16(a, b1, acc1, 0, 0, 0);
  }
  __syncthreads();

  uint16_t* Yl = Wl;
  float bias0 = bias_f[nrow0];
  float bias1 = bias_f[nrow1];
  float ps0 = 0.f, pq0 = 0.f, ps1 = 0.f, pq1 = 0.f;
  #pragma unroll
  for (int r = 0; r < 16; ++r){
    int row = m0 + (r & 3) + 8 * (r >> 2) + 4 * hi;
    bool valid = (rbase + row) < n;
    float y0 = acc0[r] + bias0;
    float y1 = acc1[r] + bias1;
    if (valid){
      ps0 += y0; pq0 += y0 * y0;
      ps1 += y1; pq1 += y1 * y1;
    }
    Yl[row * 128 + nrow0] = f2bf(y0);
    Yl[row * 128 + nrow1] = f2bf(y1);
  }
  atomicAdd(&csum[nrow0], ps0); atomicAdd(&csq[nrow0], pq0);
  atomicAdd(&csum[nrow1], ps1); atomicAdd(&csq[nrow1], pq1);
  __syncthreads();

  #pragma unroll
  for (int i = 0; i < 4; ++i){
    int id = tid + 256 * i;
    int row = id >> 4, c = id & 15;
    int gr = rbase + row;
    if (gr < n)
      *((uint4*)Yout + (size_t)gr * 16 + c) = *((const uint4*)Yl + id);
  }
  if (tid < 128){
    atomicAdd(&osum_s[stripe * 128 + tid], csum[tid]);
    atomicAdd(&osq_s[stripe * 128 + tid], csq[tid]);
  }
}

// -------- reduce BN2 stripes -> AB2 (one block) --------
__global__ void k_bncoef2(const float* __restrict__ sum_s, const float* __restrict__ sq_s,
                          const float* __restrict__ g, const float* __restrict__ be,
                          float* __restrict__ AB, float invN){
  int c = threadIdx.x;
  if (c < 128){
    float s = 0.f, q = 0.f;
    #pragma unroll 8
    for (int st = 0; st < NSTRIPE; ++st){
      s += sum_s[st * 128 + c];
      q += sq_s[st * 128 + c];
    }
    float mu = s * invN;
    float var = q * invN - mu * mu;
    float A = g[c] * rsqrtf(var + BN_EPS);
    AB[c] = A;
    AB[128 + c] = be[c] - mu * A;
  }
}

// -------- final: BN+ReLU via precomputed AB, fp32 out --------
__global__ void k_final(const uint16_t* __restrict__ Y2b, const float* __restrict__ ABg,
                        float* __restrict__ out, int total){
  __shared__ __align__(16) float AB[256];
  int tid = threadIdx.x;
  if (tid < 64){
    *(float4*)(AB + tid * 4) = *(const float4*)(ABg + tid * 4);
  }
  __syncthreads();
  int i = (blockIdx.x * 256 + tid) * 4;
  if (i >= total) return;
  uint2 v = *(const uint2*)(Y2b + i);
  int c = i & 127;
  float4 a = *(const float4*)(AB + c);
  float4 b = *(const float4*)(AB + 128 + c);
  float4 o;
  o.x = fmaxf(fmaf(bflo2f(v.x), a.x, b.x), 0.f);
  o.y = fmaxf(fmaf(bfhi2f(v.x), a.y, b.y), 0.f);
  o.z = fmaxf(fmaf(bflo2f(v.y), a.z, b.z), 0.f);
  o.w = fmaxf(fmaf(bfhi2f(v.y), a.w, b.w), 0.f);
  *(float4*)(out + i) = o;
}

extern "C" void kernel_launch(void* const* d_in, const int* in_sizes, int n_in,
                              void* d_out, int out_size, void* d_ws, size_t ws_size,
                              hipStream_t stream){
  const float* h    = (const float*)d_in[0];
  const int*   esrc = (const int*)d_in[1];
  const int*   edst = (const int*)d_in[2];
  const float* W1   = (const float*)d_in[3];
  const float* b1   = (const float*)d_in[4];
  const float* g1   = (const float*)d_in[5];
  const float* be1  = (const float*)d_in[6];
  const float* W2   = (const float*)d_in[7];
  const float* b2   = (const float*)d_in[8];
  const float* g2   = (const float*)d_in[9];
  const float* be2  = (const float*)d_in[10];
  const float* eps  = (const float*)d_in[11];
  int n = in_sizes[0] / 128;
  int E = in_sizes[1];
  (void)n_in; (void)out_size; (void)ws_size;

  int NB = (n + 255) >> 8;
  int EB = (E + 4095) >> 12;

  char* ws = (char*)d_ws;
  size_t off = 0;
  auto alloc = [&](size_t bytes) -> void* {
    void* p = ws + off;
    off += (bytes + 511) & ~(size_t)511;
    return p;
  };
  size_t feat_b = (size_t)n * 128 * 2;
  uint16_t* B1   = (uint16_t*)alloc(feat_b);        // hb  -> Y1b
  uint16_t* B2   = (uint16_t*)alloc(feat_b);        // binned -> Xb -> Y2b
  int*   row_off = (int*)alloc((size_t)(n + 1) * 4);
  int*   col_idx = (int*)alloc((size_t)E * 4);
  int*   M       = (int*)alloc((size_t)EB * NB * 4);
  int*   btot    = (int*)alloc((size_t)(NB + 1) * 4);
  int*   bbase   = (int*)alloc((size_t)(NB + 1) * 4);
  float* stats   = (float*)alloc((size_t)4 * NSTRIPE * 128 * 4);  // 4 arrays x 64 stripes x 128
  float* AB2     = (float*)alloc(256 * 4);
  uint16_t* Wt1  = (uint16_t*)alloc(128 * 128 * 2);
  uint16_t* Wt2  = (uint16_t*)alloc(128 * 128 * 2);
  float* sum1 = stats;
  float* sq1  = stats + NSTRIPE * 128;
  float* sum2 = stats + 2 * NSTRIPE * 128;
  float* sq2  = stats + 3 * NSTRIPE * 128;
  uint16_t* hb  = B1;
  uint2*   binned = (uint2*)B2;
  uint16_t* Xb  = B2;
  uint16_t* Y1b = B1;
  uint16_t* Y2b = B2;

  int total = n * 128;
  int hblocks = total / 8 / 256;
  float invN = 1.0f / (float)n;

  k_prep<<<hblocks + 16 + EB, 256, 0, stream>>>(h, hb, hblocks, W1, W2, Wt1, Wt2,
                                                stats, edst, M, E, NB);
  k_colscan<<<NB, 256, 0, stream>>>(M, btot, EB, NB);
  k_bscan  <<<1, 256, 0, stream>>>(btot, bbase, row_off, NB, n, E);
  k_bin    <<<EB, 256, 0, stream>>>(esrc, edst, M, bbase, binned, E, NB);
  k_csr    <<<NB, 256, 0, stream>>>(binned, bbase, row_off, col_idx, n);

  k_gather<<<(n + 3) / 4, 256, 0, stream>>>(hb, row_off, col_idx, eps, Xb, n);

  int gblocks = (n + 63) / 64;
  k_mgemm<false><<<gblocks, 256, 0, stream>>>(Xb, Wt1, b1,
      nullptr, nullptr, nullptr, nullptr, 0.f, Y1b, sum1, sq1, n);
  k_mgemm<true> <<<gblocks, 256, 0, stream>>>(Y1b, Wt2, b2,
      sum1, sq1, g1, be1, invN, Y2b, sum2, sq2, n);

  k_bncoef2<<<1, 128, 0, stream>>>(sum2, sq2, g2, be2, AB2, invN);
  k_final<<<(total / 4 + 255) / 256, 256, 0, stream>>>(Y2b, AB2, (float*)d_out, total);
}

// Round 9
// 305.319 us; speedup vs baseline: 1.7265x; 1.0151x over previous
//
#include <hip/hip_runtime.h>
#include <hip/hip_bf16.h>
#include <stdint.h>

#define BN_EPS 1e-5f
#define NSTRIPE 64

typedef __attribute__((ext_vector_type(8)))  short bf16x8;
typedef __attribute__((ext_vector_type(16))) float f32x16;

static __device__ __forceinline__ float bflo2f(uint32_t p){
  union { uint32_t u; float f; } c; c.u = p << 16; return c.f;
}
static __device__ __forceinline__ float bfhi2f(uint32_t p){
  union { uint32_t u; float f; } c; c.u = p & 0xffff0000u; return c.f;
}
static __device__ __forceinline__ uint16_t f2bf(float f){
  union { float f; uint32_t u; } c; c.f = f;
  uint32_t u = c.u;
  return (uint16_t)((u + 0x7fffu + ((u >> 16) & 1u)) >> 16);
}
static __device__ __forceinline__ uint32_t pack2(float a, float b){
  return (uint32_t)f2bf(a) | ((uint32_t)f2bf(b) << 16);
}

// ---- prepass: h fp32->bf16 | W transpose (plain [n][k] bf16) | zero striped stats | dst histogram ----
__global__ void k_prep(const float* __restrict__ h, uint16_t* __restrict__ hb, int hblocks,
                       const float* __restrict__ W1, const float* __restrict__ W2,
                       uint16_t* __restrict__ Wt1, uint16_t* __restrict__ Wt2,
                       float* __restrict__ stats,
                       const int* __restrict__ dst, int* __restrict__ M, int E, int NB){
  int b = blockIdx.x, t = threadIdx.x;
  if (b < hblocks){
    int i = (b * 256 + t) * 8;
    float4 a = *(const float4*)(h + i);
    float4 bb = *(const float4*)(h + i + 4);
    uint4 o;
    o.x = pack2(a.x, a.y); o.y = pack2(a.z, a.w);
    o.z = pack2(bb.x, bb.y); o.w = pack2(bb.z, bb.w);
    *(uint4*)(hb + i) = o;
    return;
  }
  if (b < hblocks + 16){
    int gid = (b - hblocks) * 256 + t;   // 0..4095
    { // zero striped stats: 4 arrays * 64 stripes * 128 cols = 32768 floats
      float4 z = make_float4(0.f, 0.f, 0.f, 0.f);
      *(float4*)(stats + gid * 8) = z;
      *(float4*)(stats + gid * 8 + 4) = z;
    }
    const float* Wf = (gid < 2048) ? W1 : W2;
    uint16_t* Wt = (gid < 2048) ? Wt1 : Wt2;
    int cid = gid & 2047;
    int nrow = cid >> 4;
    int c    = cid & 15;
    int k0 = c * 8;
    float e[8];
    #pragma unroll
    for (int j = 0; j < 8; ++j) e[j] = Wf[(k0 + j) * 128 + nrow];
    uint4 o;
    o.x = pack2(e[0], e[1]); o.y = pack2(e[2], e[3]);
    o.z = pack2(e[4], e[5]); o.w = pack2(e[6], e[7]);
    *(uint4*)(Wt + nrow * 128 + c * 8) = o;   // plain layout (B read from global)
    return;
  }
  // histogram chunk
  int eb = b - hblocks - 16;
  __shared__ int cnt[512];
  cnt[t] = 0; cnt[t + 256] = 0;
  __syncthreads();
  int base = eb * 4096;
  #pragma unroll 4
  for (int j = t; j < 4096; j += 256){
    int i = base + j;
    if (i < E) atomicAdd(&cnt[dst[i] >> 8], 1);
  }
  __syncthreads();
  size_t row = (size_t)eb * NB;
  if (t < NB) M[row + t] = cnt[t];
  int t2 = t + 256;
  if (t2 < NB) M[row + t2] = cnt[t2];
}

// ---------------- CSR chain ----------------
__global__ void k_colscan(int* __restrict__ M, int* __restrict__ btot, int EB, int NB){
  __shared__ int s[256];
  int b = blockIdx.x, t = threadIdx.x;
  int i0 = 2 * t, i1 = 2 * t + 1;
  int v0 = (i0 < EB) ? M[(size_t)i0 * NB + b] : 0;
  int v1 = (i1 < EB) ? M[(size_t)i1 * NB + b] : 0;
  s[t] = v0 + v1;
  __syncthreads();
  for (int off = 1; off < 256; off <<= 1){
    int v = (t >= off) ? s[t - off] : 0;
    __syncthreads();
    s[t] += v;
    __syncthreads();
  }
  int excl = s[t] - (v0 + v1);
  if (i0 < EB) M[(size_t)i0 * NB + b] = excl;
  if (i1 < EB) M[(size_t)i1 * NB + b] = excl + v0;
  if (t == 255) btot[b] = s[255];
}

__global__ void k_bscan(const int* __restrict__ btot, int* __restrict__ bbase,
                        int* __restrict__ row_off, int NB, int n, int E){
  __shared__ int s[256];
  int t = threadIdx.x;
  int i0 = 2 * t, i1 = 2 * t + 1;
  int v0 = (i0 < NB) ? btot[i0] : 0;
  int v1 = (i1 < NB) ? btot[i1] : 0;
  s[t] = v0 + v1;
  __syncthreads();
  for (int off = 1; off < 256; off <<= 1){
    int v = (t >= off) ? s[t - off] : 0;
    __syncthreads();
    s[t] += v;
    __syncthreads();
  }
  int excl = s[t] - (v0 + v1);
  if (i0 < NB) bbase[i0] = excl;
  if (i1 < NB) bbase[i1] = excl + v0;
  if (t == 0){ bbase[NB] = E; row_off[n] = E; }
}

__global__ void k_bin(const int* __restrict__ src, const int* __restrict__ dst,
                      const int* __restrict__ M, const int* __restrict__ bbase,
                      uint2* __restrict__ binned, int E, int NB){
  __shared__ int comb[512];
  __shared__ int cur[512];
  int t = threadIdx.x;
  size_t row = (size_t)blockIdx.x * NB;
  if (t < NB) comb[t] = bbase[t] + M[row + t];
  int t2 = t + 256;
  if (t2 < NB) comb[t2] = bbase[t2] + M[row + t2];
  cur[t] = 0; cur[t + 256] = 0;
  __syncthreads();
  int base = blockIdx.x * 4096;
  #pragma unroll 4
  for (int j = t; j < 4096; j += 256){
    int i = base + j;
    if (i < E){
      int d = dst[i];
      int b = d >> 8;
      int r = atomicAdd(&cur[b], 1);
      binned[comb[b] + r] = make_uint2((unsigned)src[i], (unsigned)d);
    }
  }
}

__global__ void k_csr(const uint2* __restrict__ binned, const int* __restrict__ bbase,
                      int* __restrict__ row_off, int* __restrict__ col_idx, int n){
  __shared__ int cnt[256];
  __shared__ int off[256];
  __shared__ int cur[256];
  int b = blockIdx.x, t = threadIdx.x;
  int e0 = bbase[b], e1 = bbase[b + 1];
  int nb0 = b << 8;
  cnt[t] = 0; cur[t] = 0;
  __syncthreads();
  int m = e1 - e0;
  for (int j = t; j < m; j += 256) atomicAdd(&cnt[binned[e0 + j].y & 255], 1);
  __syncthreads();
  int v = cnt[t];
  off[t] = v;
  __syncthreads();
  for (int o = 1; o < 256; o <<= 1){
    int u = (t >= o) ? off[t - o] : 0;
    __syncthreads();
    off[t] += u;
    __syncthreads();
  }
  int excl = off[t] - v;
  __syncthreads();
  off[t] = excl;
  if (nb0 + t < n) row_off[nb0 + t] = e0 + excl;
  __syncthreads();
  for (int j = t; j < m; j += 256){
    uint2 p = binned[e0 + j];
    int dl = p.y & 255;
    int r = atomicAdd(&cur[dl], 1);
    col_idx[e0 + off[dl] + r] = (int)p.x;
  }
}

// -------- fused gather + GEMM1: gather 64-row tile into LDS, MFMA, bias, striped stats --------
__global__ __launch_bounds__(256, 4) void k_gg(
    const uint16_t* __restrict__ hb, const int* __restrict__ row_off,
    const int* __restrict__ col_idx, const float* __restrict__ eps_p,
    const uint16_t* __restrict__ Wt, const float* __restrict__ bias_f,
    uint16_t* __restrict__ Yout, float* __restrict__ osum_s, float* __restrict__ osq_s, int n){
  __shared__ __align__(16) uint16_t Al[64 * 128];   // 16 KB, swizzled; reused as Y tile
  __shared__ float csum[128], csq[128];
  int tid = threadIdx.x;
  int rbase = blockIdx.x * 64;
  int stripe = blockIdx.x & (NSTRIPE - 1);
  int lane = tid & 63;
  int w    = tid >> 6;
  int g = lane >> 4;
  int c = lane & 15;
  const uint4* hp4 = (const uint4*)hb;
  float ce = 1.0f + eps_p[0];
  if (tid < 128){ csum[tid] = 0.f; csq[tid] = 0.f; }

  // ---- gather phase: wave w produces rows w*16 .. w*16+15 ----
  for (int it = 0; it < 16; ++it){
    int m = w * 16 + it;
    int gr = rbase + m;
    float a0=0.f,a1=0.f,a2=0.f,a3=0.f,a4=0.f,a5=0.f,a6=0.f,a7=0.f;
    if (gr < n){
      int j = row_off[gr], jend = row_off[gr + 1];
      for (; j + 16 <= jend; j += 16){
        int sA = col_idx[j + g];
        int sB = col_idx[j + 4 + g];
        int sC = col_idx[j + 8 + g];
        int sD = col_idx[j + 12 + g];
        uint4 vA = hp4[(size_t)sA * 16 + c];
        uint4 vB = hp4[(size_t)sB * 16 + c];
        uint4 vC = hp4[(size_t)sC * 16 + c];
        uint4 vD = hp4[(size_t)sD * 16 + c];
        a0 += (bflo2f(vA.x) + bflo2f(vB.x)) + (bflo2f(vC.x) + bflo2f(vD.x));
        a1 += (bfhi2f(vA.x) + bfhi2f(vB.x)) + (bfhi2f(vC.x) + bfhi2f(vD.x));
        a2 += (bflo2f(vA.y) + bflo2f(vB.y)) + (bflo2f(vC.y) + bflo2f(vD.y));
        a3 += (bfhi2f(vA.y) + bfhi2f(vB.y)) + (bfhi2f(vC.y) + bfhi2f(vD.y));
        a4 += (bflo2f(vA.z) + bflo2f(vB.z)) + (bflo2f(vC.z) + bflo2f(vD.z));
        a5 += (bfhi2f(vA.z) + bfhi2f(vB.z)) + (bfhi2f(vC.z) + bfhi2f(vD.z));
        a6 += (bflo2f(vA.w) + bflo2f(vB.w)) + (bflo2f(vC.w) + bflo2f(vD.w));
        a7 += (bfhi2f(vA.w) + bfhi2f(vB.w)) + (bfhi2f(vC.w) + bfhi2f(vD.w));
      }
      for (; j + 4 <= jend; j += 4){
        int s = col_idx[j + g];
        uint4 v = hp4[(size_t)s * 16 + c];
        a0 += bflo2f(v.x); a1 += bfhi2f(v.x);
        a2 += bflo2f(v.y); a3 += bfhi2f(v.y);
        a4 += bflo2f(v.z); a5 += bfhi2f(v.z);
        a6 += bflo2f(v.w); a7 += bfhi2f(v.w);
      }
      int rem = jend - j;
      if (rem > 0){
        int jj = j + (g < rem ? g : rem - 1);
        float wq = (g < rem) ? 1.f : 0.f;
        int s = col_idx[jj];
        uint4 v = hp4[(size_t)s * 16 + c];
        a0 = fmaf(wq, bflo2f(v.x), a0); a1 = fmaf(wq, bfhi2f(v.x), a1);
        a2 = fmaf(wq, bflo2f(v.y), a2); a3 = fmaf(wq, bfhi2f(v.y), a3);
        a4 = fmaf(wq, bflo2f(v.z), a4); a5 = fmaf(wq, bfhi2f(v.z), a5);
        a6 = fmaf(wq, bflo2f(v.w), a6); a7 = fmaf(wq, bfhi2f(v.w), a7);
      }
      a0 += __shfl_xor(a0, 16); a1 += __shfl_xor(a1, 16);
      a2 += __shfl_xor(a2, 16); a3 += __shfl_xor(a3, 16);
      a4 += __shfl_xor(a4, 16); a5 += __shfl_xor(a5, 16);
      a6 += __shfl_xor(a6, 16); a7 += __shfl_xor(a7, 16);
      a0 += __shfl_xor(a0, 32); a1 += __shfl_xor(a1, 32);
      a2 += __shfl_xor(a2, 32); a3 += __shfl_xor(a3, 32);
      a4 += __shfl_xor(a4, 32); a5 += __shfl_xor(a5, 32);
      a6 += __shfl_xor(a6, 32); a7 += __shfl_xor(a7, 32);
      if (g == 0){
        uint4 vh = hp4[(size_t)gr * 16 + c];
        a0 = fmaf(ce, bflo2f(vh.x), a0); a1 = fmaf(ce, bfhi2f(vh.x), a1);
        a2 = fmaf(ce, bflo2f(vh.y), a2); a3 = fmaf(ce, bfhi2f(vh.y), a3);
        a4 = fmaf(ce, bflo2f(vh.z), a4); a5 = fmaf(ce, bfhi2f(vh.z), a5);
        a6 = fmaf(ce, bflo2f(vh.w), a6); a7 = fmaf(ce, bfhi2f(vh.w), a7);
      }
    }
    if (g == 0){
      uint4 o;
      o.x = pack2(a0, a1); o.y = pack2(a2, a3);
      o.z = pack2(a4, a5); o.w = pack2(a6, a7);
      *(uint4*)((char*)Al + m * 256 + ((c ^ (m & 15)) * 16)) = o;
    }
  }
  __syncthreads();

  // ---- MFMA phase: A from LDS (swizzled), B straight from global (L2-hot) ----
  int hi   = lane >> 5;
  int key  = lane & 15;
  int m0   = (w & 1) * 32;
  int n0   = (w >> 1) * 64;
  int mrow = m0 + (lane & 31);
  int nrow0 = n0 + (lane & 31);
  int nrow1 = nrow0 + 32;

  f32x16 acc0, acc1;
  #pragma unroll
  for (int i = 0; i < 16; ++i){ acc0[i] = 0.f; acc1[i] = 0.f; }

  const char* Ab = (const char*)Al;
  #pragma unroll
  for (int kt = 0; kt < 8; ++kt){
    int ck = 2 * kt + hi;
    bf16x8 a  = *(const bf16x8*)(Ab + mrow * 256 + ((ck ^ key) * 16));
    bf16x8 b0 = *(const bf16x8*)(Wt + nrow0 * 128 + ck * 8);
    bf16x8 b1 = *(const bf16x8*)(Wt + nrow1 * 128 + ck * 8);
    acc0 = __builtin_amdgcn_mfma_f32_32x32x16_bf16(a, b0, acc0, 0, 0, 0);
    acc1 = __builtin_amdgcn_mfma_f32_32x32x16_bf16(a, b1, acc1, 0, 0, 0);
  }
  __syncthreads();   // all a-frag reads done; reuse Al as Y tile

  uint16_t* Yl = Al;
  float bias0 = bias_f[nrow0];
  float bias1 = bias_f[nrow1];
  float ps0 = 0.f, pq0 = 0.f, ps1 = 0.f, pq1 = 0.f;
  #pragma unroll
  for (int r = 0; r < 16; ++r){
    int row = m0 + (r & 3) + 8 * (r >> 2) + 4 * hi;
    bool valid = (rbase + row) < n;
    float y0 = acc0[r] + bias0;
    float y1 = acc1[r] + bias1;
    if (valid){
      ps0 += y0; pq0 += y0 * y0;
      ps1 += y1; pq1 += y1 * y1;
    }
    Yl[row * 128 + nrow0] = f2bf(y0);
    Yl[row * 128 + nrow1] = f2bf(y1);
  }
  atomicAdd(&csum[nrow0], ps0); atomicAdd(&csq[nrow0], pq0);
  atomicAdd(&csum[nrow1], ps1); atomicAdd(&csq[nrow1], pq1);
  __syncthreads();

  #pragma unroll
  for (int i = 0; i < 4; ++i){
    int id = tid + 256 * i;
    int row = id >> 4, cc = id & 15;
    int gr = rbase + row;
    if (gr < n)
      *((uint4*)Yout + (size_t)gr * 16 + cc) = *((const uint4*)Yl + id);
  }
  if (tid < 128){
    atomicAdd(&osum_s[stripe * 128 + tid], csum[tid]);
    atomicAdd(&osq_s[stripe * 128 + tid], csq[tid]);
  }
}

// -------- GEMM2: BN1(from stripes)+ReLU on input, MFMA (B from global), striped stats out --------
__global__ __launch_bounds__(256, 4) void k_mgemm2(
    const uint16_t* __restrict__ Ag, const uint16_t* __restrict__ Wt,
    const float* __restrict__ bias_f,
    const float* __restrict__ sin_s, const float* __restrict__ sqin_s,
    const float* __restrict__ gin, const float* __restrict__ bein, float invN,
    uint16_t* __restrict__ Yout, float* __restrict__ osum_s, float* __restrict__ osq_s, int n){
  __shared__ __align__(16) uint16_t Al[64 * 128];
  __shared__ float csum[128], csq[128];
  __shared__ __align__(16) float ABl[256];
  int tid = threadIdx.x;
  int rbase = blockIdx.x * 64;
  int stripe = blockIdx.x & (NSTRIPE - 1);

  if (tid < 128){
    float s = 0.f, q = 0.f;
    #pragma unroll 8
    for (int st = 0; st < NSTRIPE; ++st){
      s += sin_s[st * 128 + tid];
      q += sqin_s[st * 128 + tid];
    }
    float mu = s * invN;
    float var = q * invN - mu * mu;
    float A = gin[tid] * rsqrtf(var + BN_EPS);
    ABl[tid] = A;
    ABl[128 + tid] = bein[tid] - mu * A;
    csum[tid] = 0.f; csq[tid] = 0.f;
  }
  __syncthreads();

  #pragma unroll
  for (int i = 0; i < 4; ++i){
    int f = tid + 256 * i;
    int m = f >> 4, c = f & 15;
    int gr = rbase + m;
    uint4 v = make_uint4(0, 0, 0, 0);
    if (gr < n){
      v = *(const uint4*)(Ag + (size_t)gr * 128 + c * 8);
      int k0 = c * 8;
      float4 ka0 = *(const float4*)(ABl + k0);
      float4 ka1 = *(const float4*)(ABl + k0 + 4);
      float4 kb0 = *(const float4*)(ABl + 128 + k0);
      float4 kb1 = *(const float4*)(ABl + 128 + k0 + 4);
      float e0 = fmaxf(fmaf(bflo2f(v.x), ka0.x, kb0.x), 0.f);
      float e1 = fmaxf(fmaf(bfhi2f(v.x), ka0.y, kb0.y), 0.f);
      float e2 = fmaxf(fmaf(bflo2f(v.y), ka0.z, kb0.z), 0.f);
      float e3 = fmaxf(fmaf(bfhi2f(v.y), ka0.w, kb0.w), 0.f);
      float e4 = fmaxf(fmaf(bflo2f(v.z), ka1.x, kb1.x), 0.f);
      float e5 = fmaxf(fmaf(bfhi2f(v.z), ka1.y, kb1.y), 0.f);
      float e6 = fmaxf(fmaf(bflo2f(v.w), ka1.z, kb1.z), 0.f);
      float e7 = fmaxf(fmaf(bfhi2f(v.w), ka1.w, kb1.w), 0.f);
      v.x = pack2(e0, e1); v.y = pack2(e2, e3);
      v.z = pack2(e4, e5); v.w = pack2(e6, e7);
    }
    *(uint4*)((char*)Al + m * 256 + ((c ^ (m & 15)) * 16)) = v;
  }
  __syncthreads();

  int lane = tid & 63;
  int w    = tid >> 6;
  int hi   = lane >> 5;
  int key  = lane & 15;
  int m0   = (w & 1) * 32;
  int n0   = (w >> 1) * 64;
  int mrow = m0 + (lane & 31);
  int nrow0 = n0 + (lane & 31);
  int nrow1 = nrow0 + 32;

  f32x16 acc0, acc1;
  #pragma unroll
  for (int i = 0; i < 16; ++i){ acc0[i] = 0.f; acc1[i] = 0.f; }

  const char* Ab = (const char*)Al;
  #pragma unroll
  for (int kt = 0; kt < 8; ++kt){
    int ck = 2 * kt + hi;
    bf16x8 a  = *(const bf16x8*)(Ab + mrow * 256 + ((ck ^ key) * 16));
    bf16x8 b0 = *(const bf16x8*)(Wt + nrow0 * 128 + ck * 8);
    bf16x8 b1 = *(const bf16x8*)(Wt + nrow1 * 128 + ck * 8);
    acc0 = __builtin_amdgcn_mfma_f32_32x32x16_bf16(a, b0, acc0, 0, 0, 0);
    acc1 = __builtin_amdgcn_mfma_f32_32x32x16_bf16(a, b1, acc1, 0, 0, 0);
  }
  __syncthreads();

  uint16_t* Yl = Al;
  float bias0 = bias_f[nrow0];
  float bias1 = bias_f[nrow1];
  float ps0 = 0.f, pq0 = 0.f, ps1 = 0.f, pq1 = 0.f;
  #pragma unroll
  for (int r = 0; r < 16; ++r){
    int row = m0 + (r & 3) + 8 * (r >> 2) + 4 * hi;
    bool valid = (rbase + row) < n;
    float y0 = acc0[r] + bias0;
    float y1 = acc1[r] + bias1;
    if (valid){
      ps0 += y0; pq0 += y0 * y0;
      ps1 += y1; pq1 += y1 * y1;
    }
    Yl[row * 128 + nrow0] = f2bf(y0);
    Yl[row * 128 + nrow1] = f2bf(y1);
  }
  atomicAdd(&csum[nrow0], ps0); atomicAdd(&csq[nrow0], pq0);
  atomicAdd(&csum[nrow1], ps1); atomicAdd(&csq[nrow1], pq1);
  __syncthreads();

  #pragma unroll
  for (int i = 0; i < 4; ++i){
    int id = tid + 256 * i;
    int row = id >> 4, cc = id & 15;
    int gr = rbase + row;
    if (gr < n)
      *((uint4*)Yout + (size_t)gr * 16 + cc) = *((const uint4*)Yl + id);
  }
  if (tid < 128){
    atomicAdd(&osum_s[stripe * 128 + tid], csum[tid]);
    atomicAdd(&osq_s[stripe * 128 + tid], csq[tid]);
  }
}

// -------- reduce BN2 stripes -> AB2 (one block) --------
__global__ void k_bncoef2(const float* __restrict__ sum_s, const float* __restrict__ sq_s,
                          const float* __restrict__ g, const float* __restrict__ be,
                          float* __restrict__ AB, float invN){
  int c = threadIdx.x;
  if (c < 128){
    float s = 0.f, q = 0.f;
    #pragma unroll 8
    for (int st = 0; st < NSTRIPE; ++st){
      s += sum_s[st * 128 + c];
      q += sq_s[st * 128 + c];
    }
    float mu = s * invN;
    float var = q * invN - mu * mu;
    float A = g[c] * rsqrtf(var + BN_EPS);
    AB[c] = A;
    AB[128 + c] = be[c] - mu * A;
  }
}

// -------- final: BN+ReLU via precomputed AB, fp32 out --------
__global__ void k_final(const uint16_t* __restrict__ Y2b, const float* __restrict__ ABg,
                        float* __restrict__ out, int total){
  __shared__ __align__(16) float AB[256];
  int tid = threadIdx.x;
  if (tid < 64){
    *(float4*)(AB + tid * 4) = *(const float4*)(ABg + tid * 4);
  }
  __syncthreads();
  int i = (blockIdx.x * 256 + tid) * 4;
  if (i >= total) return;
  uint2 v = *(const uint2*)(Y2b + i);
  int c = i & 127;
  float4 a = *(const float4*)(AB + c);
  float4 b = *(const float4*)(AB + 128 + c);
  float4 o;
  o.x = fmaxf(fmaf(bflo2f(v.x), a.x, b.x), 0.f);
  o.y = fmaxf(fmaf(bfhi2f(v.x), a.y, b.y), 0.f);
  o.z = fmaxf(fmaf(bflo2f(v.y), a.z, b.z), 0.f);
  o.w = fmaxf(fmaf(bfhi2f(v.y), a.w, b.w), 0.f);
  *(float4*)(out + i) = o;
}

extern "C" void kernel_launch(void* const* d_in, const int* in_sizes, int n_in,
                              void* d_out, int out_size, void* d_ws, size_t ws_size,
                              hipStream_t stream){
  const float* h    = (const float*)d_in[0];
  const int*   esrc = (const int*)d_in[1];
  const int*   edst = (const int*)d_in[2];
  const float* W1   = (const float*)d_in[3];
  const float* b1   = (const float*)d_in[4];
  const float* g1   = (const float*)d_in[5];
  const float* be1  = (const float*)d_in[6];
  const float* W2   = (const float*)d_in[7];
  const float* b2   = (const float*)d_in[8];
  const float* g2   = (const float*)d_in[9];
  const float* be2  = (const float*)d_in[10];
  const float* eps  = (const float*)d_in[11];
  int n = in_sizes[0] / 128;
  int E = in_sizes[1];
  (void)n_in; (void)out_size; (void)ws_size;

  int NB = (n + 255) >> 8;
  int EB = (E + 4095) >> 12;

  char* ws = (char*)d_ws;
  size_t off = 0;
  auto alloc = [&](size_t bytes) -> void* {
    void* p = ws + off;
    off += (bytes + 511) & ~(size_t)511;
    return p;
  };
  size_t feat_b = (size_t)n * 128 * 2;
  uint16_t* B1   = (uint16_t*)alloc(feat_b);        // hb (live through k_gg) -> Y2b
  uint16_t* B2   = (uint16_t*)alloc(feat_b);        // binned (dead after csr) -> Y1b
  int*   row_off = (int*)alloc((size_t)(n + 1) * 4);
  int*   col_idx = (int*)alloc((size_t)E * 4);
  int*   M       = (int*)alloc((size_t)EB * NB * 4);
  int*   btot    = (int*)alloc((size_t)(NB + 1) * 4);
  int*   bbase   = (int*)alloc((size_t)(NB + 1) * 4);
  float* stats   = (float*)alloc((size_t)4 * NSTRIPE * 128 * 4);
  float* AB2     = (float*)alloc(256 * 4);
  uint16_t* Wt1  = (uint16_t*)alloc(128 * 128 * 2);
  uint16_t* Wt2  = (uint16_t*)alloc(128 * 128 * 2);
  float* sum1 = stats;
  float* sq1  = stats + NSTRIPE * 128;
  float* sum2 = stats + 2 * NSTRIPE * 128;
  float* sq2  = stats + 3 * NSTRIPE * 128;
  uint16_t* hb  = B1;
  uint2*   binned = (uint2*)B2;
  uint16_t* Y1b = B2;   // overwrites binned (dead)
  uint16_t* Y2b = B1;   // overwrites hb (dead after k_gg)

  int total = n * 128;
  int hblocks = total / 8 / 256;
  float invN = 1.0f / (float)n;

  k_prep<<<hblocks + 16 + EB, 256, 0, stream>>>(h, hb, hblocks, W1, W2, Wt1, Wt2,
                                                stats, edst, M, E, NB);
  k_colscan<<<NB, 256, 0, stream>>>(M, btot, EB, NB);
  k_bscan  <<<1, 256, 0, stream>>>(btot, bbase, row_off, NB, n, E);
  k_bin    <<<EB, 256, 0, stream>>>(esrc, edst, M, bbase, binned, E, NB);
  k_csr    <<<NB, 256, 0, stream>>>(binned, bbase, row_off, col_idx, n);

  int gblocks = (n + 63) / 64;
  k_gg<<<gblocks, 256, 0, stream>>>(hb, row_off, col_idx, eps, Wt1, b1,
                                    Y1b, sum1, sq1, n);
  k_mgemm2<<<gblocks, 256, 0, stream>>>(Y1b, Wt2, b2,
      sum1, sq1, g1, be1, invN, Y2b, sum2, sq2, n);

  k_bncoef2<<<1, 128, 0, stream>>>(sum2, sq2, g2, be2, AB2, invN);
  k_final<<<(total / 4 + 255) / 256, 256, 0, stream>>>(Y2b, AB2, (float*)d_out, total);
}